// Round 9
// baseline (679.728 us; speedup 1.0000x reference)
//
#include <hip/hip_runtime.h>
#include <hip/hip_bf16.h>
#include <type_traits>
#include <math.h>

typedef __hip_bfloat16 bf16_t;

// Problem constants
#define BB 4
#define LL 2048
#define DM 1024
#define DI 2048
#define NS 16
#define DTR 64
#define DFF 4096
#define MTOK (BB*LL)   // 8192
#define NC 32          // scan chunks
#define CL (LL/NC)     // 64 timesteps per chunk
#define TT 16          // scan LDS tile (timesteps); CL/TT = 4 tiles
#define KS 4           // x_proj split-K factor

// raw 2^x (saves the log2e mul inside __expf; arg pre-scaled by caller)
#if defined(__has_builtin)
#if __has_builtin(__builtin_amdgcn_exp2f)
#define EXP2F(x) __builtin_amdgcn_exp2f(x)
#endif
#endif
#ifndef EXP2F
#define EXP2F(x) exp2f(x)
#endif
#define LOG2E 1.44269504088896340736f

// ---------- helpers ----------
__device__ __forceinline__ float b2f_lo(unsigned u) {
    union { unsigned x; float f; } c; c.x = u << 16; return c.f;
}
__device__ __forceinline__ float b2f_hi(unsigned u) {
    union { unsigned x; float f; } c; c.x = u & 0xffff0000u; return c.f;
}
__device__ __forceinline__ void unpack8(uint4 v, float* o) {
    o[0] = b2f_lo(v.x); o[1] = b2f_hi(v.x);
    o[2] = b2f_lo(v.y); o[3] = b2f_hi(v.y);
    o[4] = b2f_lo(v.z); o[5] = b2f_hi(v.z);
    o[6] = b2f_lo(v.w); o[7] = b2f_hi(v.w);
}

typedef __attribute__((ext_vector_type(8))) short bf16x8;
typedef __attribute__((ext_vector_type(4))) float f32x4;

__device__ __forceinline__ void gld_lds16(const void* g, void* l) {
    __builtin_amdgcn_global_load_lds(
        (const __attribute__((address_space(1))) void*)g,
        (__attribute__((address_space(3))) void*)l, 16, 0, 0);
}

// shared scheduling macros
#define G8_BAR  __builtin_amdgcn_s_barrier()
#define G8_SB   __builtin_amdgcn_sched_barrier(0)
#define G8_LGKM do { asm volatile("s_waitcnt lgkmcnt(0)" ::: "memory"); G8_SB; } while (0)
#define G8_VM8  do { asm volatile("s_waitcnt vmcnt(8)"   ::: "memory"); G8_SB; } while (0)
#define G8_VM6  do { asm volatile("s_waitcnt vmcnt(6)"   ::: "memory"); G8_SB; } while (0)
#define G8_VM4  do { asm volatile("s_waitcnt vmcnt(4)"   ::: "memory"); G8_SB; } while (0)
#define G8_VM2  do { asm volatile("s_waitcnt vmcnt(2)"   ::: "memory"); G8_SB; } while (0)
#define G8_VM0  do { asm volatile("s_waitcnt vmcnt(0)"   ::: "memory"); G8_SB; } while (0)

// ---------- dtype detection (bf16 vs fp32 input buffers) ----------
__global__ void detect_dtype_kernel(const unsigned* __restrict__ x, int* __restrict__ flag)
{
    __shared__ int cnt;
    if (threadIdx.x == 0) cnt = 0;
    __syncthreads();
    int c = 0;
    for (int i = threadIdx.x; i < 4096; i += 256) {
        unsigned w = x[i];
        int e = (w >> 7) & 0xFF;
        c += (e >= 100 && e <= 140) ? 1 : 0;
    }
    atomicAdd(&cnt, c);
    __syncthreads();
    if (threadIdx.x == 0) *flag = (cnt > 2048) ? 1 : 0;
}

// ---------- canonicalize ALL inputs to bf16 in ONE launch ----------
struct CvtDesc {
    const void* src[14];
    bf16_t*     dst[14];
    int         cum[15];
};

__global__ __launch_bounds__(256)
void convert_all(CvtDesc d, const int* __restrict__ flag, int total8)
{
    int i = blockIdx.x * 256 + threadIdx.x;
    if (i >= total8) return;
    int t = 0;
#pragma unroll 1
    while (i >= d.cum[t + 1]) ++t;
    int j = i - d.cum[t];
    if (*flag) {
        ((uint4*)d.dst[t])[j] = ((const uint4*)d.src[t])[j];
    } else {
        const float4* s = (const float4*)d.src[t] + (size_t)j * 2;
        float4 a = s[0], b = s[1];
        bf16_t o[8];
        o[0] = __float2bfloat16(a.x); o[1] = __float2bfloat16(a.y);
        o[2] = __float2bfloat16(a.z); o[3] = __float2bfloat16(a.w);
        o[4] = __float2bfloat16(b.x); o[5] = __float2bfloat16(b.y);
        o[6] = __float2bfloat16(b.z); o[7] = __float2bfloat16(b.w);
        ((uint4*)d.dst[t])[j] = *(uint4*)o;
    }
}

// ================== 8-phase 256x256 GEMM (HK-style schedule) ==================
// + XCD-aware block remap (T1); + LDS-staged coalesced epilogue (kills the
//   2x write amplification from 2B scattered stores seen in r8 counters).
#define G8_NK 16

template <int EPI, bool SPLIT>   // EPI: 0 none, 2 bias+relu
__global__ __launch_bounds__(512, 2)
void gemm8(const bf16_t* __restrict__ A, const bf16_t* __restrict__ W,
           bf16_t* __restrict__ C, bf16_t* __restrict__ C2,
           const bf16_t* __restrict__ bias, int ldc)
{
    __shared__ __align__(16) bf16_t ldsmem[2][2][256 * 64]; // [buf][op 0=A,1=B]

    const int tid  = threadIdx.x;
    const int lane = tid & 63;
    const int wv   = tid >> 6;      // 0..7
    const int wm   = wv >> 2;       // 0..1
    const int wn   = wv & 3;        // 0..3
    const int r16  = lane & 15;
    const int q    = lane >> 4;

    // XCD-aware bijective remap (nwg % 8 == 0 for all our launches)
    const int lin = blockIdx.y * gridDim.x + blockIdx.x;
    const int per = (gridDim.x * gridDim.y) >> 3;
    const int l2  = (lin & 7) * per + (lin >> 3);
    const int m0  = (l2 % gridDim.x) * 256;
    const int n0  = (l2 / gridDim.x) * 256;

    const int x0 = q ^ (r16 & 7);          // swizzled chunk idx, kk=0
    const int x1 = (4 + q) ^ (r16 & 7);    // kk=1

    const int srow = tid >> 3;                       // 0..63
    const int scol = (tid & 7) ^ (srow & 7);
    const bf16_t* Abase = A + (size_t)(m0 + srow) * 1024 + scol * 8;
    const bf16_t* Wbase = W + (size_t)(n0 + srow) * 1024 + scol * 8;
    const int woff = wv * 1024;

    const bf16x8* L8 = (const bf16x8*)ldsmem;
    char*         Lb = (char*)ldsmem;

    f32x4  acc[8][4] = {};
    bf16x8 af[4][2];
    bf16x8 bfr[2][2][2];

    auto stA = [&](int bufc, int tile, int half) {
        const bf16_t* g = Abase + (size_t)half * (128 * 1024) + tile * 64;
        char* l = Lb + (size_t)(bufc * 2 + 0) * 32768 + half * 16384 + woff;
        gld_lds16(g, l);
        gld_lds16(g + 64 * 1024, l + 8192);
    };
    auto stB = [&](int bufc, int tile, int half) {
        const bf16_t* g = Wbase + (size_t)half * (128 * 1024) + tile * 64;
        char* l = Lb + (size_t)(bufc * 2 + 1) * 32768 + half * 16384 + woff;
        gld_lds16(g, l);
        gld_lds16(g + 64 * 1024, l + 8192);
    };
    auto rdA = [&](int bufc, int mh) {
#pragma unroll
        for (int mf = 0; mf < 4; ++mf) {
            int rb = (bufc * 2 + 0) * 2048 + (wm * 128 + mh * 64 + mf * 16 + r16) * 8;
            af[mf][0] = L8[rb + x0];
            af[mf][1] = L8[rb + x1];
        }
    };
    auto rdB = [&](int bufc, int nh) {
#pragma unroll
        for (int nf = 0; nf < 2; ++nf) {
            int rb = (bufc * 2 + 1) * 2048 + (wn * 64 + nh * 32 + nf * 16 + r16) * 8;
            bfr[nh][nf][0] = L8[rb + x0];
            bfr[nh][nf][1] = L8[rb + x1];
        }
    };
    auto mmQ = [&](int mh, int nh) {
#pragma unroll
        for (int mf = 0; mf < 4; ++mf)
#pragma unroll
            for (int nf = 0; nf < 2; ++nf) {
                acc[mh*4+mf][nh*2+nf] = __builtin_amdgcn_mfma_f32_16x16x32_bf16(
                    af[mf][0], bfr[nh][nf][0], acc[mh*4+mf][nh*2+nf], 0, 0, 0);
                acc[mh*4+mf][nh*2+nf] = __builtin_amdgcn_mfma_f32_16x16x32_bf16(
                    af[mf][1], bfr[nh][nf][1], acc[mh*4+mf][nh*2+nf], 0, 0, 0);
            }
    };

#define G8_PH(mh, nh) do { G8_BAR; G8_LGKM;                      \
        __builtin_amdgcn_s_setprio(1); mmQ(mh, nh);              \
        __builtin_amdgcn_s_setprio(0); G8_SB; G8_BAR; G8_SB; } while (0)

    stA(0, 0, 0); stA(0, 0, 1);
    stB(0, 0, 0); stB(0, 0, 1);
    stB(1, 1, 0); stB(1, 1, 1);
    G8_VM4;
    G8_BAR; G8_SB;

    for (int i = 0; i < G8_NK / 2 - 1; ++i) {
        const int v1 = 2 * i + 1, u2 = 2 * i + 2, v2 = 2 * i + 3;
        rdA(0,0); rdB(0,0); stA(1, v1, 0);         G8_PH(0,0);
        rdB(0,1);           stA(1, v1, 1);         G8_PH(0,1);
        rdA(0,1);           stB(0, u2, 0);         G8_PH(1,0);
                            stB(0, u2, 1); G8_VM4; G8_PH(1,1);
        rdA(1,0); rdB(1,0); stA(0, u2, 0);         G8_PH(0,0);
        rdB(1,1);           stA(0, u2, 1);         G8_PH(0,1);
        rdA(1,1);           stB(1, v2, 0);         G8_PH(1,0);
                            stB(1, v2, 1); G8_VM4; G8_PH(1,1);
    }
    rdA(0,0); rdB(0,0); stA(1, G8_NK - 1, 0); G8_PH(0,0);
    rdB(0,1);           stA(1, G8_NK - 1, 1); G8_PH(0,1);
    rdA(0,1);                                 G8_PH(1,0);
                        G8_VM0;               G8_PH(1,1);
    rdA(1,0); rdB(1,0);                       G8_PH(0,0);
    rdB(1,1);                                 G8_PH(0,1);
    rdA(1,1);                                 G8_PH(1,0);
                                              G8_PH(1,1);

    // ---- coalesced epilogue: stage C-tile through LDS (dead after K-loop),
    //      flush as 16B stores covering full 512B rows. Two 128-row halves,
    //      row stride 258 bf16 (+2 pad: write ~conflict-free, read 4-way max).
    bf16_t* Cb = C;
    int csub = 0;
    if (SPLIT && n0 >= 2048) { Cb = C2; csub = 2048; }

    bf16_t* T = (bf16_t*)ldsmem;          // 128 x 258 bf16 = 66048 B <= 131072
#pragma unroll
    for (int h = 0; h < 2; ++h) {
        if (wm == h) {
#pragma unroll
            for (int b = 0; b < 4; ++b) {
                int col = wn * 64 + (b >> 1) * 32 + (b & 1) * 16 + r16;
                float bv = 0.f;
                if (EPI >= 1) bv = __bfloat162float(bias[n0 + col]);
#pragma unroll
                for (int a = 0; a < 8; ++a) {
#pragma unroll
                    for (int r = 0; r < 4; ++r) {
                        int lr = (a >> 2) * 64 + (a & 3) * 16 + q * 4 + r;
                        float v = acc[a][b][r];
                        if (EPI >= 1) v += bv;
                        if (EPI == 2) v = v > 0.f ? v : 0.f;
                        T[lr * 258 + col] = __float2bfloat16(v);
                    }
                }
            }
        }
        __syncthreads();
        {
            int row = tid >> 2, qt = tid & 3;
            int rowg = m0 + h * 128 + row;
            const char* src = (const char*)T + row * 516 + qt * 128;
            char* dstg = (char*)(Cb + (size_t)rowg * ldc + (n0 - csub) + qt * 64);
#pragma unroll
            for (int k = 0; k < 8; ++k) {
                uint4 v = *(const uint4*)(src + k * 16);
                *(uint4*)(dstg + k * 16) = v;
            }
        }
        __syncthreads();
    }
#undef G8_PH
}

// ================== 8-phase 256x128 GEMM (narrow-N variant) ==================
// + XCD-aware block remap (T1).
template <int LDK, int NKT, int EPI, bool DYN>   // EPI: 0 none, 1 +bias
__global__ __launch_bounds__(512, 2)
void gemm8n(const bf16_t* __restrict__ A, const bf16_t* __restrict__ W,
            bf16_t* __restrict__ C, const bf16_t* __restrict__ bias, int ldc,
            const int* oflag, int c_row_off)
{
    __shared__ __align__(16) bf16_t ldsmem[2][24576];   // 49152 B per buf: A 32K | B 16K

    const int tid  = threadIdx.x;
    const int lane = tid & 63;
    const int wv   = tid >> 6;      // 0..7
    const int wm   = wv >> 2;       // 0..1 (128 rows)
    const int wn   = wv & 3;        // 0..3 (32 cols)
    const int r16  = lane & 15;
    const int q    = lane >> 4;

    const int lin = blockIdx.y * gridDim.x + blockIdx.x;
    const int per = (gridDim.x * gridDim.y) >> 3;
    const int l2  = (lin & 7) * per + (lin >> 3);
    const int m0  = (l2 % gridDim.x) * 256;
    const int n0  = (l2 / gridDim.x) * 128;

    const int x0 = q ^ (r16 & 7);
    const int x1 = (4 + q) ^ (r16 & 7);

    const int srow = tid >> 3;                       // 0..63
    const int scol = (tid & 7) ^ (srow & 7);
    const bf16_t* Abase = A + (size_t)(m0 + srow) * LDK + scol * 8;
    const bf16_t* Wbase = W + (size_t)(n0 + srow) * LDK + scol * 8;
    const int woff = wv * 1024;

    const bf16x8* L8 = (const bf16x8*)ldsmem;        // 16B chunk units
    char*         Lb = (char*)ldsmem;

    f32x4  acc[8][2] = {};
    bf16x8 af[4][2];          // [mf][kk]
    bf16x8 bfr[2][2];         // [nf][kk]

    auto stA = [&](int bufc, int tile, int half) {
        const bf16_t* g = Abase + (size_t)half * (128 * LDK) + tile * 64;
        char* l = Lb + (size_t)bufc * 49152 + half * 16384 + woff;
        gld_lds16(g, l);
        gld_lds16(g + (size_t)64 * LDK, l + 8192);
    };
    auto stB = [&](int bufc, int tile) {
        const bf16_t* g = Wbase + tile * 64;
        char* l = Lb + (size_t)bufc * 49152 + 32768 + woff;
        gld_lds16(g, l);
        gld_lds16(g + (size_t)64 * LDK, l + 8192);
    };
    auto rdA = [&](int bufc, int mh) {
#pragma unroll
        for (int mf = 0; mf < 4; ++mf) {
            int rb = bufc * 3072 + (wm * 128 + mh * 64 + mf * 16 + r16) * 8;
            af[mf][0] = L8[rb + x0];
            af[mf][1] = L8[rb + x1];
        }
    };
    auto rdB = [&](int bufc) {
#pragma unroll
        for (int nf = 0; nf < 2; ++nf) {
            int rb = bufc * 3072 + 2048 + (wn * 32 + nf * 16 + r16) * 8;
            bfr[nf][0] = L8[rb + x0];
            bfr[nf][1] = L8[rb + x1];
        }
    };
    auto mmP = [&](int mh) {
#pragma unroll
        for (int mf = 0; mf < 4; ++mf)
#pragma unroll
            for (int nf = 0; nf < 2; ++nf) {
                acc[mh*4+mf][nf] = __builtin_amdgcn_mfma_f32_16x16x32_bf16(
                    af[mf][0], bfr[nf][0], acc[mh*4+mf][nf], 0, 0, 0);
                acc[mh*4+mf][nf] = __builtin_amdgcn_mfma_f32_16x16x32_bf16(
                    af[mf][1], bfr[nf][1], acc[mh*4+mf][nf], 0, 0, 0);
            }
    };

#define GN_PH(mh) do { G8_BAR; G8_LGKM;                          \
        __builtin_amdgcn_s_setprio(1); mmP(mh);                  \
        __builtin_amdgcn_s_setprio(0); G8_SB; G8_BAR; G8_SB; } while (0)

    stA(0, 0, 0); stA(0, 0, 1);
    stB(0, 0);
    stB(1, 1);
    G8_VM2;
    G8_BAR; G8_SB;

    for (int i = 0; i < NKT / 2 - 1; ++i) {
        const int v1 = 2 * i + 1, u2 = 2 * i + 2, v2 = 2 * i + 3;
        rdA(0,0); rdB(0); stA(1, v1, 0); stA(1, v1, 1); GN_PH(0);   // P1
        rdA(0,1);         stB(0, u2); G8_VM2;           GN_PH(1);   // P2
        rdA(1,0); rdB(1); stA(0, u2, 0); stA(0, u2, 1); GN_PH(0);   // P3
        rdA(1,1);         stB(1, v2); G8_VM2;           GN_PH(1);   // P4
    }
    rdA(0,0); rdB(0); stA(1, NKT - 1, 0); stA(1, NKT - 1, 1); GN_PH(0);
    rdA(0,1);         G8_VM0;                                 GN_PH(1);
    rdA(1,0); rdB(1);                                         GN_PH(0);
    rdA(1,1);                                                 GN_PH(1);

    int of = 1;
    if constexpr (DYN) of = *oflag;
#pragma unroll
    for (int nf = 0; nf < 2; ++nf) {
        int colg = n0 + wn * 32 + nf * 16 + r16;
        float bv = 0.f;
        if (EPI >= 1) bv = __bfloat162float(bias[colg]);
#pragma unroll
        for (int a = 0; a < 8; ++a) {
#pragma unroll
            for (int r = 0; r < 4; ++r) {
                int rowg = m0 + wm * 128 + a * 16 + q * 4 + r;
                float v = acc[a][nf][r];
                if (EPI >= 1) v += bv;
                if constexpr (DYN) {
                    size_t idx = (size_t)(c_row_off + rowg) * ldc + colg;
                    if (of) ((bf16_t*)C)[idx] = __float2bfloat16(v);
                    else    ((float*)C)[idx]  = v;
                } else {
                    C[(size_t)rowg * ldc + colg] = __float2bfloat16(v);
                }
            }
        }
    }
#undef GN_PH
}

// ---------- GEMM: 2-phase fallback for small/odd shapes ----------
#define TM 128
#define TN 128
#define TK 64

template <typename OutT, int EPI, bool DYN, bool EDGE>
__global__ __launch_bounds__(256, 2)
void gemm_bt(const bf16_t* __restrict__ A, int lda,
             const bf16_t* __restrict__ W, int ldw,
             OutT* __restrict__ C, int ldc,
             OutT* __restrict__ C2, int nsplit,
             const bf16_t* __restrict__ bias,
             int M, int N, int K,
             const int* oflag, int c_row_off)
{
    __shared__ bf16_t sA[TM * TK];
    __shared__ bf16_t sB[TN * TK];

    const int tid  = threadIdx.x;
    const int lane = tid & 63;
    const int wv   = tid >> 6;
    const int m0   = blockIdx.x * TM;
    const int n0   = blockIdx.y * TN;
    const int wm   = (wv >> 1) * 64;
    const int wn   = (wv & 1) * 64;
    const int r16  = lane & 15;
    const int q    = lane >> 4;

    int of = 1;
    if constexpr (DYN) of = *oflag;

    f32x4 acc[4][4] = {};

    for (int k0 = 0; k0 < K; k0 += TK) {
#pragma unroll
        for (int i = 0; i < 4; ++i) {
            int c    = (i * 4 + wv) * 64 + lane;
            int row  = c >> 3;
            int col8 = c & 7;
            const bf16_t* ga = A + (size_t)(m0 + row) * lda + k0 + col8 * 8;
            gld_lds16(ga, (char*)sA + (size_t)(i * 4 + wv) * 1024);
            int nrow = n0 + row;
            if (EDGE && nrow > N - 1) nrow = N - 1;
            const bf16_t* gb = W + (size_t)nrow * ldw + k0 + col8 * 8;
            gld_lds16(gb, (char*)sB + (size_t)(i * 4 + wv) * 1024);
        }
        __syncthreads();

        const bf16x8* sA8 = (const bf16x8*)sA;
        const bf16x8* sB8 = (const bf16x8*)sB;
#pragma unroll
        for (int kk = 0; kk < 2; ++kk) {
            bf16x8 af[4], bfr[4];
#pragma unroll
            for (int i = 0; i < 4; ++i)
                af[i] = sA8[(wm + i * 16 + r16) * 8 + kk * 4 + q];
#pragma unroll
            for (int j = 0; j < 4; ++j)
                bfr[j] = sB8[(wn + j * 16 + r16) * 8 + kk * 4 + q];
#pragma unroll
            for (int i = 0; i < 4; ++i)
#pragma unroll
                for (int j = 0; j < 4; ++j)
                    acc[i][j] = __builtin_amdgcn_mfma_f32_16x16x32_bf16(
                        af[i], bfr[j], acc[i][j], 0, 0, 0);
        }
        __syncthreads();
    }

    OutT* Cb = C;
    int csub = 0;
    if (C2 != nullptr && n0 >= nsplit) { Cb = C2; csub = nsplit; }

#pragma unroll
    for (int j = 0; j < 4; ++j) {
        int colg = n0 + wn + j * 16 + r16;
        if (EDGE && colg >= N) continue;
        float bv = 0.f;
        if (EPI >= 1) bv = __bfloat162float(bias[colg]);
#pragma unroll
        for (int i = 0; i < 4; ++i) {
#pragma unroll
            for (int r = 0; r < 4; ++r) {
                int rowg = m0 + wm + i * 16 + q * 4 + r;
                if (EDGE && rowg >= M) continue;
                float v = acc[i][j][r];
                if (EPI >= 1) v += bv;
                if (EPI == 2) v = v > 0.f ? v : 0.f;
                if (EPI == 3) v = (v > 20.f) ? v : log1pf(__expf(v));
                if constexpr (DYN) {
                    size_t idx = (size_t)(c_row_off + rowg) * ldc + colg;
                    if (of) ((bf16_t*)Cb)[idx] = __float2bfloat16(v);
                    else    ((float*)Cb)[idx]  = v;
                } else if constexpr (std::is_same<OutT, float>::value) {
                    Cb[(size_t)rowg * ldc + (colg - csub)] = v;
                } else {
                    Cb[(size_t)rowg * ldc + (colg - csub)] = __float2bfloat16(v);
                }
            }
        }
    }
}

// ---------- x_proj split-K GEMM ----------
__global__ __launch_bounds__(256, 2)
void gemm_xproj_splitk(const bf16_t* __restrict__ A,
                       const bf16_t* __restrict__ W,
                       float* __restrict__ part, int M)
{
    __shared__ bf16_t sA[TM * TK];
    __shared__ bf16_t sB[TN * TK];

    const int tid  = threadIdx.x;
    const int lane = tid & 63;
    const int wv   = tid >> 6;
    const int m0   = blockIdx.x * TM;
    const int kz   = blockIdx.z;
    const int wm   = (wv >> 1) * 64;
    const int wn   = (wv & 1) * 64;
    const int r16  = lane & 15;
    const int q    = lane >> 4;

    f32x4 acc[4][4] = {};

    const int kbeg = kz * (2048 / KS);
    for (int k0 = kbeg; k0 < kbeg + 2048 / KS; k0 += TK) {
#pragma unroll
        for (int i = 0; i < 4; ++i) {
            int c    = (i * 4 + wv) * 64 + lane;
            int row  = c >> 3;
            int col8 = c & 7;
            const bf16_t* ga = A + (size_t)(m0 + row) * DI + k0 + col8 * 8;
            gld_lds16(ga, (char*)sA + (size_t)(i * 4 + wv) * 1024);
            int nrow = row; if (nrow > 95) nrow = 95;
            const bf16_t* gb = W + (size_t)nrow * DI + k0 + col8 * 8;
            gld_lds16(gb, (char*)sB + (size_t)(i * 4 + wv) * 1024);
        }
        __syncthreads();

        const bf16x8* sA8 = (const bf16x8*)sA;
        const bf16x8* sB8 = (const bf16x8*)sB;
#pragma unroll
        for (int kk = 0; kk < 2; ++kk) {
            bf16x8 af[4], bfr[4];
#pragma unroll
            for (int i = 0; i < 4; ++i)
                af[i] = sA8[(wm + i * 16 + r16) * 8 + kk * 4 + q];
#pragma unroll
            for (int j = 0; j < 4; ++j)
                bfr[j] = sB8[(wn + j * 16 + r16) * 8 + kk * 4 + q];
#pragma unroll
            for (int i = 0; i < 4; ++i)
#pragma unroll
                for (int j = 0; j < 4; ++j)
                    acc[i][j] = __builtin_amdgcn_mfma_f32_16x16x32_bf16(
                        af[i], bfr[j], acc[i][j], 0, 0, 0);
        }
        __syncthreads();
    }

#pragma unroll
    for (int j = 0; j < 4; ++j) {
        int colg = wn + j * 16 + r16;
        if (colg >= 96) continue;
#pragma unroll
        for (int i = 0; i < 4; ++i) {
#pragma unroll
            for (int r = 0; r < 4; ++r) {
                int rowg = m0 + wm + i * 16 + q * 4 + r;
                part[((size_t)kz * M + rowg) * 96 + colg] = acc[i][j][r];
            }
        }
    }
}

__global__ __launch_bounds__(256)
void xproj_reduce(const float* __restrict__ part, bf16_t* __restrict__ xdbl,
                  float* __restrict__ x32, int M)
{
    int i = blockIdx.x * 256 + threadIdx.x;
    int n = M * 96;
    if (i >= n) return;
    float s = part[i] + part[(size_t)n + i] + part[2 * (size_t)n + i] + part[3 * (size_t)n + i];
    xdbl[i] = __float2bfloat16(s);
    if (x32) x32[i] = s;
}

// ---------- depthwise causal conv (k=4) + bias + SiLU ----------
__global__ __launch_bounds__(256)
void conv_silu_kernel(const bf16_t* __restrict__ u,
                      const bf16_t* __restrict__ cw,
                      const bf16_t* __restrict__ cb,
                      bf16_t* __restrict__ uc,
                      int Mrows)
{
    int idx = blockIdx.x * 256 + threadIdx.x;
    int eg  = idx & 255;
    int row = idx >> 8;
    if (row >= Mrows) return;
    int t = row & (LL - 1);
    int b = row >> 11;
    int e0 = eg * 8;

    float wf[32];
    {
        const uint4* wp = (const uint4*)(cw + (size_t)e0 * 4);
        uint4 w0 = wp[0], w1 = wp[1], w2 = wp[2], w3 = wp[3];
        unpack8(w0, wf); unpack8(w1, wf + 8); unpack8(w2, wf + 16); unpack8(w3, wf + 24);
    }
    float bias[8];
    unpack8(*(const uint4*)(cb + e0), bias);

    float uk[4][8];
#pragma unroll
    for (int k = 0; k < 4; ++k) {
        int tt = t - 3 + k;
        if (tt >= 0) {
            uint4 uv = *(const uint4*)(u + (size_t)(b * LL + tt) * DI + e0);
            unpack8(uv, uk[k]);
        } else {
#pragma unroll
            for (int j = 0; j < 8; ++j) uk[k][j] = 0.f;
        }
    }
    bf16_t out8[8];
#pragma unroll
    for (int j = 0; j < 8; ++j) {
        float a = bias[j];
#pragma unroll
        for (int k = 0; k < 4; ++k) a += wf[j * 4 + k] * uk[k][j];
        a = a / (1.f + __expf(-a));
        out8[j] = __float2bfloat16(a);
    }
    *(uint4*)(uc + (size_t)row * DI + e0) = *(uint4*)out8;
}

// ---------- chunked parallel scan: LDS-staged tiles, counted-vmcnt pipeline ---
__global__ __launch_bounds__(256, 4)
void scan_pass1(const bf16_t* __restrict__ uc, const bf16_t* __restrict__ dtb,
                const float* __restrict__ x32, const bf16_t* __restrict__ A_log,
                float* __restrict__ hfin, float* __restrict__ Ssum, int lgG)
{
    __shared__ __align__(16) char sm1[36864];   // U[2] 0/8K, D[2] 16/24K, B 32K..36K
    const int tid  = threadIdx.x;
    const int lane = tid & 63;
    const int wv   = tid >> 6;
    const int bid  = blockIdx.x;
    const int eb   = bid & 7;
    const int rem  = bid >> 3;
    const int b    = rem & ((1 << lgG) - 1);
    const int chunk = rem >> lgG;
    const int e0   = eb * 256;
    const int e    = e0 + tid;
    const int t0   = chunk * CL;

    const bf16_t* ub = uc  + (size_t)(b * LL + t0) * DI;
    const bf16_t* db = dtb + (size_t)(b * LL + t0) * DI;
    const float*  xr = x32 + (size_t)(b * LL + t0) * 96 + 64;

    char* const U[2] = { sm1, sm1 + 8192 };
    char* const D[2] = { sm1 + 16384, sm1 + 24576 };
    char* const Bl   = sm1 + 32768;

    auto stage2 = [&](const bf16_t* src, char* dst, int trow0) {
        const int c8 = (lane & 31) * 8;
        const int r0 = 2 * wv + (lane >> 5);
        gld_lds16(src + (size_t)(trow0 + r0) * DI + e0 + c8, dst + wv * 1024 + lane * 16);
        gld_lds16(src + (size_t)(trow0 + r0 + 8) * DI + e0 + c8, dst + (wv + 4) * 1024 + lane * 16);
    };
    // stage whole chunk's B panel (64 steps x 64B): 256 chunks of 16B, 1/thread
    {
        int s = tid >> 2, p = tid & 3;
        gld_lds16(xr + (size_t)s * 96 + p * 4, Bl + tid * 16);      // 1 op
    }
    stage2(ub, U[0], 0);  stage2(db, D[0], 0);                      // 4 ops
    stage2(ub, U[1], TT); stage2(db, D[1], TT);                     // 4 ops

    // prologue (covers staging latency): 16 exps
    float alf[16];
    {
        uint4 v0 = *(const uint4*)(A_log + (size_t)e * NS);
        uint4 v1 = *(const uint4*)(A_log + (size_t)e * NS + 8);
        unpack8(v0, alf); unpack8(v1, alf + 8);
    }
    float a0 = -__expf(alf[0]) * LOG2E;
    float Aa2[16];
    int fast = 1;
#pragma unroll
    for (int n = 0; n < 16; ++n) {
        Aa2[n] = -__expf(alf[n]) * LOG2E;
        float ideal = (float)(n + 1) * a0;
        fast = fast && (fabsf(Aa2[n] - ideal) <= 0.02f * fabsf(ideal));
    }
    int allfast = __syncthreads_and(fast);

    float h[16];
#pragma unroll
    for (int j = 0; j < 16; ++j) h[j] = 0.f;
    float Ss = 0.f;

#define P1_CMP(K, FAST) do {                                                  \
        const char* Ut = U[(K) & 1]; const char* Dt = D[(K) & 1];             \
        _Pragma("unroll")                                                     \
        for (int t = 0; t < TT; ++t) {                                        \
            float cu  = __bfloat162float(*(const bf16_t*)(Ut + t * 512 + tid * 2)); \
            float cdt = __bfloat162float(*(const bf16_t*)(Dt + t * 512 + tid * 2)); \
            const float* bc = (const float*)(Bl + ((K) * TT + t) * 64);       \
            float du = cdt * cu; Ss += cdt;                                   \
            if (FAST) {                                                       \
                float r = EXP2F(cdt * a0);                                    \
                float r2 = r * r, r4 = r2 * r2, r8 = r4 * r4;                 \
                float dA = r, dB = r8 * r;                                    \
                _Pragma("unroll")                                             \
                for (int j = 0; j < 8; ++j) { h[j] = dA * h[j] + du * bc[j]; dA *= r; } \
                _Pragma("unroll")                                             \
                for (int j = 8; j < 16; ++j) { h[j] = dB * h[j] + du * bc[j]; dB *= r; } \
            } else {                                                          \
                _Pragma("unroll")                                             \
                for (int j = 0; j < 16; ++j) {                                \
                    float dA = EXP2F(cdt * Aa2[j]);                           \
                    h[j] = dA * h[j] + du * bc[j]; }                          \
            }                                                                 \
        } } while (0)

#define P1_SEQ(FAST) do {                                                     \
        G8_VM4; G8_BAR; G8_SB;                                                \
        P1_CMP(0, FAST); G8_LGKM; G8_BAR; G8_SB;                              \
        stage2(ub, U[0], 2 * TT); stage2(db, D[0], 2 * TT);                   \
        G8_VM4; G8_BAR; G8_SB;                                                \
        P1_CMP(1, FAST); G8_LGKM; G8_BAR; G8_SB;                              \
        stage2(ub, U[1], 3 * TT); stage2(db, D[1], 3 * TT);                   \
        G8_VM4; G8_BAR; G8_SB;                                                \
        P1_CMP(2, FAST); G8_LGKM; G8_BAR; G8_SB;                              \
        G8_VM0; G8_BAR; G8_SB;                                                \
        P1_CMP(3, FAST);                                                      \
    } while (0)

    if (allfast) P1_SEQ(true); else P1_SEQ(false);
#undef P1_SEQ
#undef P1_CMP

    size_t base = (size_t)(b * NC + chunk) * NS * DI + e;
#pragma unroll
    for (int j = 0; j < 16; ++j) hfin[base + (size_t)j * DI] = h[j];
    Ssum[(size_t)(b * NC + chunk) * DI + e] = Ss;
}

__global__ __launch_bounds__(256)
void scan_pass2(const float* __restrict__ Ssum, const bf16_t* __restrict__ A_log,
                float* __restrict__ hfin)
{
    int idx = blockIdx.x * 256 + threadIdx.x;
    int e = idx & (DI - 1);
    int rem = idx >> 11;
    int n = rem & (NS - 1);
    int b = rem >> 4;
    float Aa2 = -__expf(__bfloat162float(A_log[(size_t)e * NS + n])) * LOG2E;
    float h = 0.f;
    for (int c = 0; c < NC; ++c) {
        size_t a = ((size_t)(b * NC + c) * NS + n) * DI + e;
        float S  = Ssum[(size_t)(b * NC + c) * DI + e];
        float hf = hfin[a];
        hfin[a] = h;
        h = EXP2F(Aa2 * S) * h + hf;
    }
}

__global__ __launch_bounds__(256, 2)
void scan_pass3(const bf16_t* __restrict__ uc, const bf16_t* __restrict__ dtb,
                const float* __restrict__ x32, bf16_t* __restrict__ zy,
                const bf16_t* __restrict__ A_log, const bf16_t* __restrict__ Dp,
                const float* __restrict__ hin, int lgG)
{
    __shared__ __align__(16) char sm3[65536];  // U 0/8K, D 16/24K, Z 32/40K, Y 48K, BC 56K
    const int tid  = threadIdx.x;
    const int lane = tid & 63;
    const int wv   = tid >> 6;
    const int bid  = blockIdx.x;
    const int eb   = bid & 7;
    const int rem  = bid >> 3;
    const int b    = rem & ((1 << lgG) - 1);
    const int chunk = rem >> lgG;
    const int e0   = eb * 256;
    const int e    = e0 + tid;
    const int t0   = chunk * CL;

    const bf16_t* ub = uc  + (size_t)(b * LL + t0) * DI;
    const bf16_t* db = dtb + (size_t)(b * LL + t0) * DI;
    bf16_t*       zb = zy  + (size_t)(b * LL + t0) * DI;   // z in, y out
    const float*  xr = x32 + (size_t)(b * LL + t0) * 96 + 64;

    char* const U[2] = { sm3, sm3 + 8192 };
    char* const D[2] = { sm3 + 16384, sm3 + 24576 };
    char* const Z[2] = { sm3 + 32768, sm3 + 40960 };
    char* const Y    = sm3 + 49152;
    char* const BC   = sm3 + 57344;

    auto stage2 = [&](const bf16_t* src, char* dst, int trow0) {
        const int c8 = (lane & 31) * 8;
        const int r0 = 2 * wv + (lane >> 5);
        gld_lds16(src + (size_t)(trow0 + r0) * DI + e0 + c8, dst + wv * 1024 + lane * 16);
        gld_lds16(src + (size_t)(trow0 + r0 + 8) * DI + e0 + c8, dst + (wv + 4) * 1024 + lane * 16);
    };
    // stage whole chunk's B+C panel (64 steps x 128B = 8KB): 512 chunks, 2/thread
    {
        int s1 = tid >> 3, p1 = tid & 7;
        gld_lds16(xr + (size_t)s1 * 96 + p1 * 4, BC + tid * 16);
        gld_lds16(xr + (size_t)(s1 + 32) * 96 + p1 * 4, BC + 4096 + tid * 16);
    }                                                                // 2 ops
    stage2(ub, U[0], 0);  stage2(db, D[0], 0);  stage2(zb, Z[0], 0);   // 6
    stage2(ub, U[1], TT); stage2(db, D[1], TT); stage2(zb, Z[1], TT);  // 6

    // prologue (covers staging latency)
    float alf[16];
    {
        uint4 v0 = *(const uint4*)(A_log + (size_t)e * NS);
        uint4 v1 = *(const uint4*)(A_log + (size_t)e * NS + 8);
        unpack8(v0, alf); unpack8(v1, alf + 8);
    }
    float a0 = -__expf(alf[0]) * LOG2E;
    float Aa2[16];
    int fast = 1;
#pragma unroll
    for (int n = 0; n < 16; ++n) {
        Aa2[n] = -__expf(alf[n]) * LOG2E;
        float ideal = (float)(n + 1) * a0;
        fast = fast && (fabsf(Aa2[n] - ideal) <= 0.02f * fabsf(ideal));
    }
    int allfast = __syncthreads_and(fast);

    float Dv = __bfloat162float(Dp[e]);
    size_t hbase = (size_t)(b * NC + chunk) * NS * DI + e;
    float h[16];
#pragma unroll
    for (int j = 0; j < 16; ++j) h[j] = hin[hbase + (size_t)j * DI];

    auto yflush = [&](int K) {
        const int r0 = tid >> 5;
        const int c  = (tid & 31) * 16;
        uint4 v0 = *(const uint4*)(Y + r0 * 512 + c);
        uint4 v1 = *(const uint4*)(Y + (r0 + 8) * 512 + c);
        *(uint4*)(zb + (size_t)(K * TT + r0) * DI + e0 + (tid & 31) * 8)     = v0;
        *(uint4*)(zb + (size_t)(K * TT + r0 + 8) * DI + e0 + (tid & 31) * 8) = v1;
    };

#define P3_CMP(K, FAST) do {                                                  \
        const char* Ut = U[(K) & 1]; const char* Dt = D[(K) & 1];             \
        const char* Zt = Z[(K) & 1];                                          \
        _Pragma("unroll")                                                     \
        for (int t = 0; t < TT; ++t) {                                        \
            float cu  = __bfloat162float(*(const bf16_t*)(Ut + t * 512 + tid * 2)); \
            float cdt = __bfloat162float(*(const bf16_t*)(Dt + t * 512 + tid * 2)); \
            float cz  = __bfloat162float(*(const bf16_t*)(Zt + t * 512 + tid * 2)); \
            const float* bc = (const float*)(BC + ((K) * TT + t) * 128);      \
            float du = cdt * cu;                                              \
            if (FAST) {                                                       \
                float r = EXP2F(cdt * a0);                                    \
                float r2 = r * r, r4 = r2 * r2, r8 = r4 * r4;                 \
                float dA = r, dB = r8 * r;                                    \
                _Pragma("unroll")                                             \
                for (int j = 0; j < 8; ++j) { h[j] = dA * h[j] + du * bc[j]; dA *= r; } \
                _Pragma("unroll")                                             \
                for (int j = 8; j < 16; ++j) { h[j] = dB * h[j] + du * bc[j]; dB *= r; } \
            } else {                                                          \
                _Pragma("unroll")                                             \
                for (int j = 0; j < 16; ++j) {                                \
                    float dA = EXP2F(cdt * Aa2[j]);                           \
                    h[j] = dA * h[j] + du * bc[j]; }                          \
            }                                                                 \
            float y1 = 0.f, y2 = 0.f;                                         \
            _Pragma("unroll")                                                 \
            for (int j = 0; j < 8; ++j)  y1 += h[j] * bc[16 + j];             \
            _Pragma("unroll")                                                 \
            for (int j = 8; j < 16; ++j) y2 += h[j] * bc[16 + j];             \
            float yv  = y1 + y2;                                              \
            float sil = cz / (1.f + __expf(-cz));                             \
            *(bf16_t*)(Y + t * 512 + tid * 2) =                               \
                __float2bfloat16((yv + cu * Dv) * sil);                       \
        } } while (0)

#define P3_SEQ(FAST) do {                                                     \
        G8_VM6; G8_BAR; G8_SB;                                                \
        P3_CMP(0, FAST); G8_LGKM; G8_BAR; G8_SB;                              \
        yflush(0);                                                            \
        stage2(ub, U[0], 2*TT); stage2(db, D[0], 2*TT); stage2(zb, Z[0], 2*TT); \
        G8_VM8; G8_BAR; G8_SB;                                                \
        P3_CMP(1, FAST); G8_LGKM; G8_BAR; G8_SB;                              \
        yflush(1);                                                            \
        stage2(ub, U[1], 3*TT); stage2(db, D[1], 3*TT); stage2(zb, Z[1], 3*TT); \
        G8_VM8; G8_BAR; G8_SB;                                                \
        P3_CMP(2, FAST); G8_LGKM; G8_BAR; G8_SB;                              \
        yflush(2);                                                            \
        G8_VM2; G8_BAR; G8_SB;                                                \
        P3_CMP(3, FAST); G8_LGKM; G8_BAR; G8_SB;                              \
        yflush(3);                                                            \
    } while (0)

    if (allfast) P3_SEQ(true); else P3_SEQ(false);
#undef P3_SEQ
#undef P3_CMP
}

// ---------- serial scan fallback (reads bf16 xdbl) ----------
__global__ __launch_bounds__(64)
void scan_kernel(const bf16_t* __restrict__ uc,
                 const bf16_t* __restrict__ dt,
                 const bf16_t* __restrict__ xdbl,
                 bf16_t* __restrict__ zy,
                 const bf16_t* __restrict__ A_log,
                 const bf16_t* __restrict__ Dp)
{
    int idx = blockIdx.x * 64 + threadIdx.x;
    int e = idx & (DI - 1);
    int b = idx >> 11;

    float Aa[NS];
#pragma unroll
    for (int n = 0; n < NS; ++n)
        Aa[n] = -__expf(__bfloat162float(A_log[e * NS + n]));
    float Dv = __bfloat162float(Dp[e]);
    float h[NS];
#pragma unroll
    for (int n = 0; n < NS; ++n) h[n] = 0.f;

    const bf16_t* up  = uc   + (size_t)b * LL * DI + e;
    const bf16_t* dp  = dt   + (size_t)b * LL * DI + e;
    const bf16_t* zp  = zy   + (size_t)b * LL * DI + e;
    const bf16_t* bcp = xdbl + (size_t)b * LL * 96 + 64;
    bf16_t*       yp  = zy   + (size_t)b * LL * DI + e;

    float nu  = __bfloat162float(*up);
    float ndt = __bfloat162float(*dp);
    float nz  = __bfloat162float(*zp);
    uint4 nb0 = *(const uint4*)(bcp);
    uint4 nb1 = *(const uint4*)(bcp + 8);
    uint4 nc0 = *(const uint4*)(bcp + 16);
    uint4 nc1 = *(const uint4*)(bcp + 24);

    for (int t = 0; t < LL; ++t) {
        float cu = nu, cdt = ndt, cz = nz;
        uint4 b0 = nb0, b1 = nb1, c0 = nc0, c1 = nc1;
        if (t + 1 < LL) {
            up += DI; dp += DI; zp += DI; bcp += 96;
            nu  = __bfloat162float(*up);
            ndt = __bfloat162float(*dp);
            nz  = __bfloat162float(*zp);
            nb0 = *(const uint4*)(bcp);
            nb1 = *(const uint4*)(bcp + 8);
            nc0 = *(const uint4*)(bcp + 16);
            nc1 = *(const uint4*)(bcp + 24);
        }
        float Bv[NS], Cv[NS];
        unpack8(b0, Bv); unpack8(b1, Bv + 8);
        unpack8(c0, Cv); unpack8(c1, Cv + 8);

        float du = cdt * cu;
        float yv = 0.f;
#pragma unroll
        for (int n = 0; n < NS; ++n) {
            float dA = __expf(cdt * Aa[n]);
            h[n] = dA * h[n] + du * Bv[n];
            yv += h[n] * Cv[n];
        }
        float sil  = cz / (1.f + __expf(-cz));
        float outv = (yv + cu * Dv) * sil;
        *yp = __float2bfloat16(outv);
        yp += DI;
    }
}

// ---------- launcher ----------
extern "C" void kernel_launch(void* const* d_in, const int* in_sizes, int n_in,
                              void* d_out, int out_size, void* d_ws, size_t ws_size,
                              hipStream_t stream)
{
    char* ws = (char*)d_ws;
    int* flag = (int*)ws;
    size_t cur = 256;
    auto alloc = [&](size_t bytes) { bf16_t* p = (bf16_t*)(ws + cur); cur += bytes; return p; };

    const size_t o_xb = cur;
    bf16_t* xb   = alloc((size_t)MTOK * DM * 2);      // 16 MiB
    bf16_t* w_in = alloc((size_t)2 * DI * DM * 2);    //  8 MiB
    bf16_t* w_o  = alloc((size_t)DM * DI * 2);
    bf16_t* w_l1 = alloc((size_t)DFF * DM * 2);
    bf16_t* w_l2 = alloc((size_t)DM * DFF * 2);
    bf16_t* w_xp = alloc((size_t)96 * DI * 2);
    bf16_t* w_dt = alloc((size_t)DI * DTR * 2);
    bf16_t* cw   = alloc((size_t)DI * 4 * 2);
    bf16_t* cb   = alloc((size_t)DI * 2);
    bf16_t* dpb  = alloc((size_t)DI * 2);
    bf16_t* alog = alloc((size_t)DI * NS * 2);
    bf16_t* dd   = alloc((size_t)DI * 2);
    bf16_t* l1b  = alloc((size_t)DFF * 2);
    bf16_t* l2b  = alloc((size_t)DM * 2 + 2048);
    cur = (cur + 255) & ~(size_t)255;
    const size_t o_pipe = cur;

    detect_dtype_kernel<<<1, 256, 0, stream>>>((const unsigned*)d_in[0], flag);

    {
        CvtDesc d;
        const void* ss[14] = { d_in[0], d_in[1], d_in[9], d_in[10], d_in[12], d_in[4],
                               d_in[5], d_in[2], d_in[3], d_in[6], d_in[7], d_in[8],
                               d_in[11], d_in[13] };
        bf16_t* dd_[14]    = { xb, w_in, w_o, w_l1, w_l2, w_xp,
                               w_dt, cw, cb, dpb, alog, dd, l1b, l2b };
        size_t  nn[14]     = { (size_t)MTOK*DM, (size_t)2*DI*DM, (size_t)DM*DI,
                               (size_t)DFF*DM, (size_t)DM*DFF, (size_t)96*DI,
                               (size_t)DI*DTR, (size_t)DI*4, (size_t)DI, (size_t)DI,
                               (size_t)DI*NS, (size_t)DI, (size_t)DFF, (size_t)DM };
        int c = 0; d.cum[0] = 0;
        for (int i = 0; i < 14; ++i) {
            d.src[i] = ss[i]; d.dst[i] = dd_[i];
            c += (int)(nn[i] / 8); d.cum[i + 1] = c;
        }
        convert_all<<<(c + 255) / 256, 256, 0, stream>>>(d, flag, c);
    }

    auto pipe = [&](int Gq) { return (size_t)Gq * LL * 96 * 2 + 3ull * Gq * LL * DI * 2; };
    auto scr  = [&](int Gq) {
        return (size_t)Gq * NC * NS * DI * 4 + (size_t)Gq * NC * DI * 4 + (size_t)Gq * LL * 96 * 4;
    };

    int G; bool chunked; size_t scr_off;
    if      (ws_size >= o_pipe + pipe(4))            { G = 4; chunked = true;  scr_off = o_xb; }
    else if (ws_size >= o_pipe + pipe(2) + scr(2))   { G = 2; chunked = true;  scr_off = o_pipe + pipe(2); }
    else if (ws_size >= o_pipe + pipe(1) + scr(1))   { G = 1; chunked = true;  scr_off = o_pipe + pipe(1); }
    else                                             { G = 1; chunked = false; scr_off = o_pipe + pipe(1); }
    const int lgG = (G == 4) ? 2 : (G == 2 ? 1 : 0);

    const size_t hfin_sz = (size_t)G * NC * NS * DI * 4;
    const size_t ssum_sz = (size_t)G * NC * DI * 4;

    for (int g0 = 0; g0 < BB; g0 += G) {
        const int    Mg      = G * LL;
        const size_t xdbl_sz = (size_t)Mg * 96 * 2;
        const size_t big     = (size_t)Mg * DI * 2;

        bf16_t* xdbl = (bf16_t*)(ws + o_pipe);
        bf16_t* ubuf = (bf16_t*)(ws + o_pipe + xdbl_sz);
        bf16_t* dtb  = ubuf;
        bf16_t* zbuf = (bf16_t*)(ws + o_pipe + xdbl_sz + big);
        bf16_t* uc   = (bf16_t*)(ws + o_pipe + xdbl_sz + 2 * big);
        bf16_t* my   = uc;
        bf16_t* hh   = (bf16_t*)(ws + o_pipe);
        float*  xpp  = (float*)(ws + scr_off);
        float*  x32  = chunked ? (float*)(ws + scr_off + hfin_sz + ssum_sz) : nullptr;

        const bf16_t* x_g = xb + (size_t)g0 * LL * DM;

        dim3 blk(256);
        const int gx = Mg / TM;

        // 1. in_proj merged (N=4096, K=1024): 8-phase 256^2; cols<2048 -> ubuf, else zbuf
        gemm8<0, true><<<dim3(Mg / 256, 16), 512, 0, stream>>>(
            x_g, w_in, ubuf, zbuf, nullptr, DI);
        // 2. depthwise conv + SiLU -> uc
        conv_silu_kernel<<<Mg, 256, 0, stream>>>(ubuf, cw, cb, uc, Mg);
        // 3. x_proj split-K -> partials -> xdbl (bf16) + x32 (fp32)
        gemm_xproj_splitk<<<dim3(gx, 1, KS), blk, 0, stream>>>(uc, w_xp, xpp, Mg);
        xproj_reduce<<<(Mg * 96 + 255) / 256, 256, 0, stream>>>(xpp, xdbl, x32, Mg);
        // 4. dt_proj + softplus -> dtb
        gemm_bt<bf16_t, 3, false, false><<<dim3(gx, DI / TN), blk, 0, stream>>>(
            xdbl, 96, w_dt, DTR, dtb, DI, nullptr, 0, dpb, Mg, DI, DTR, nullptr, 0);
        // 5. selective scan + gating; y overwrites zbuf (LDS-staged tiles)
        if (chunked) {
            float* hfin = (float*)(ws + scr_off);
            float* Ssum = (float*)(ws + scr_off + hfin_sz);
            scan_pass1<<<G * NC * (DI / 256), 256, 0, stream>>>(uc, dtb, x32, alog, hfin, Ssum, lgG);
            scan_pass2<<<G * (NS * DI / 256), 256, 0, stream>>>(Ssum, alog, hfin);
            scan_pass3<<<G * NC * (DI / 256), 256, 0, stream>>>(uc, dtb, x32, zbuf, alog, dd, hfin, lgG);
        } else {
            scan_kernel<<<(G * DI) / 64, 64, 0, stream>>>(uc, dtb, xdbl, zbuf, alog, dd);
        }
        // 6. out_proj -> my (8-phase 256x128, K=2048)
        gemm8n<2048, 32, 0, false><<<dim3(Mg / 256, DM / 128), 512, 0, stream>>>(
            zbuf, w_o, my, nullptr, DM, nullptr, 0);
        // 7. lin1 + bias + relu -> hh (8-phase 256^2)
        gemm8<2, false><<<dim3(Mg / 256, 16), 512, 0, stream>>>(
            my, w_l1, hh, nullptr, l1b, DFF);
        // 8. lin2 + bias -> d_out (8-phase 256x128, K=4096, dtype per flag)
        gemm8n<4096, 64, 1, true><<<dim3(Mg / 256, DM / 128), 512, 0, stream>>>(
            hh, w_l2, (bf16_t*)d_out, l2b, DM, (const int*)ws, g0 * LL);
    }
}

// Round 10
// 589.361 us; speedup vs baseline: 1.1533x; 1.1533x over previous
//
#include <hip/hip_runtime.h>
#include <hip/hip_bf16.h>
#include <type_traits>
#include <math.h>

typedef __hip_bfloat16 bf16_t;

// Problem constants
#define BB 4
#define LL 2048
#define DM 1024
#define DI 2048
#define NS 16
#define DTR 64
#define DFF 4096
#define MTOK (BB*LL)   // 8192
#define NC 32          // scan chunks
#define CL (LL/NC)     // 64 timesteps per chunk
#define TT 16          // scan LDS tile (timesteps); CL/TT = 4 tiles
#define KS 4           // x_proj split-K factor

// raw 2^x (saves the log2e mul inside __expf; arg pre-scaled by caller)
#if defined(__has_builtin)
#if __has_builtin(__builtin_amdgcn_exp2f)
#define EXP2F(x) __builtin_amdgcn_exp2f(x)
#endif
#endif
#ifndef EXP2F
#define EXP2F(x) exp2f(x)
#endif
#define LOG2E 1.44269504088896340736f

// ---------- helpers ----------
__device__ __forceinline__ float b2f_lo(unsigned u) {
    union { unsigned x; float f; } c; c.x = u << 16; return c.f;
}
__device__ __forceinline__ float b2f_hi(unsigned u) {
    union { unsigned x; float f; } c; c.x = u & 0xffff0000u; return c.f;
}
__device__ __forceinline__ void unpack8(uint4 v, float* o) {
    o[0] = b2f_lo(v.x); o[1] = b2f_hi(v.x);
    o[2] = b2f_lo(v.y); o[3] = b2f_hi(v.y);
    o[4] = b2f_lo(v.z); o[5] = b2f_hi(v.z);
    o[6] = b2f_lo(v.w); o[7] = b2f_hi(v.w);
}

typedef __attribute__((ext_vector_type(8))) short bf16x8;
typedef __attribute__((ext_vector_type(4))) float f32x4;

__device__ __forceinline__ void gld_lds16(const void* g, void* l) {
    __builtin_amdgcn_global_load_lds(
        (const __attribute__((address_space(1))) void*)g,
        (__attribute__((address_space(3))) void*)l, 16, 0, 0);
}

// shared scheduling macros
#define G8_BAR  __builtin_amdgcn_s_barrier()
#define G8_SB   __builtin_amdgcn_sched_barrier(0)
#define G8_LGKM do { asm volatile("s_waitcnt lgkmcnt(0)" ::: "memory"); G8_SB; } while (0)
#define G8_VM8  do { asm volatile("s_waitcnt vmcnt(8)"   ::: "memory"); G8_SB; } while (0)
#define G8_VM6  do { asm volatile("s_waitcnt vmcnt(6)"   ::: "memory"); G8_SB; } while (0)
#define G8_VM4  do { asm volatile("s_waitcnt vmcnt(4)"   ::: "memory"); G8_SB; } while (0)
#define G8_VM2  do { asm volatile("s_waitcnt vmcnt(2)"   ::: "memory"); G8_SB; } while (0)
#define G8_VM0  do { asm volatile("s_waitcnt vmcnt(0)"   ::: "memory"); G8_SB; } while (0)

// ---------- dtype detection (bf16 vs fp32 input buffers) ----------
__global__ void detect_dtype_kernel(const unsigned* __restrict__ x, int* __restrict__ flag)
{
    __shared__ int cnt;
    if (threadIdx.x == 0) cnt = 0;
    __syncthreads();
    int c = 0;
    for (int i = threadIdx.x; i < 4096; i += 256) {
        unsigned w = x[i];
        int e = (w >> 7) & 0xFF;
        c += (e >= 100 && e <= 140) ? 1 : 0;
    }
    atomicAdd(&cnt, c);
    __syncthreads();
    if (threadIdx.x == 0) *flag = (cnt > 2048) ? 1 : 0;
}

// ---------- canonicalize ALL inputs to bf16 in ONE launch ----------
struct CvtDesc {
    const void* src[14];
    bf16_t*     dst[14];
    int         cum[15];
};

__global__ __launch_bounds__(256)
void convert_all(CvtDesc d, const int* __restrict__ flag, int total8)
{
    int i = blockIdx.x * 256 + threadIdx.x;
    if (i >= total8) return;
    int t = 0;
#pragma unroll 1
    while (i >= d.cum[t + 1]) ++t;
    int j = i - d.cum[t];
    if (*flag) {
        ((uint4*)d.dst[t])[j] = ((const uint4*)d.src[t])[j];
    } else {
        const float4* s = (const float4*)d.src[t] + (size_t)j * 2;
        float4 a = s[0], b = s[1];
        bf16_t o[8];
        o[0] = __float2bfloat16(a.x); o[1] = __float2bfloat16(a.y);
        o[2] = __float2bfloat16(a.z); o[3] = __float2bfloat16(a.w);
        o[4] = __float2bfloat16(b.x); o[5] = __float2bfloat16(b.y);
        o[6] = __float2bfloat16(b.z); o[7] = __float2bfloat16(b.w);
        ((uint4*)d.dst[t])[j] = *(uint4*)o;
    }
}

// ================== 8-phase 256x256 GEMM (HK-style schedule) ==================
// r9 post-mortem: XCD remap (FETCH 49->135MB, L2 thrash) and LDS epilogue
// (bank conflicts, WRITE up) both reverted. Only change vs r8: epilogue store
// ORDER -- column-groups (b) innermost so each row's 4x32B segments issue
// back-to-back and 64B lines assemble in L2 before eviction.
#define G8_NK 16

template <int EPI, bool SPLIT>   // EPI: 0 none, 2 bias+relu
__global__ __launch_bounds__(512, 2)
void gemm8(const bf16_t* __restrict__ A, const bf16_t* __restrict__ W,
           bf16_t* __restrict__ C, bf16_t* __restrict__ C2,
           const bf16_t* __restrict__ bias, int ldc)
{
    __shared__ __align__(16) bf16_t ldsmem[2][2][256 * 64]; // [buf][op 0=A,1=B]

    const int tid  = threadIdx.x;
    const int lane = tid & 63;
    const int wv   = tid >> 6;      // 0..7
    const int wm   = wv >> 2;       // 0..1
    const int wn   = wv & 3;        // 0..3
    const int r16  = lane & 15;
    const int q    = lane >> 4;
    const int m0   = blockIdx.x * 256;
    const int n0   = blockIdx.y * 256;

    const int x0 = q ^ (r16 & 7);          // swizzled chunk idx, kk=0
    const int x1 = (4 + q) ^ (r16 & 7);    // kk=1

    const int srow = tid >> 3;                       // 0..63
    const int scol = (tid & 7) ^ (srow & 7);
    const bf16_t* Abase = A + (size_t)(m0 + srow) * 1024 + scol * 8;
    const bf16_t* Wbase = W + (size_t)(n0 + srow) * 1024 + scol * 8;
    const int woff = wv * 1024;

    const bf16x8* L8 = (const bf16x8*)ldsmem;
    char*         Lb = (char*)ldsmem;

    f32x4  acc[8][4] = {};
    bf16x8 af[4][2];
    bf16x8 bfr[2][2][2];

    auto stA = [&](int bufc, int tile, int half) {
        const bf16_t* g = Abase + (size_t)half * (128 * 1024) + tile * 64;
        char* l = Lb + (size_t)(bufc * 2 + 0) * 32768 + half * 16384 + woff;
        gld_lds16(g, l);
        gld_lds16(g + 64 * 1024, l + 8192);
    };
    auto stB = [&](int bufc, int tile, int half) {
        const bf16_t* g = Wbase + (size_t)half * (128 * 1024) + tile * 64;
        char* l = Lb + (size_t)(bufc * 2 + 1) * 32768 + half * 16384 + woff;
        gld_lds16(g, l);
        gld_lds16(g + 64 * 1024, l + 8192);
    };
    auto rdA = [&](int bufc, int mh) {
#pragma unroll
        for (int mf = 0; mf < 4; ++mf) {
            int rb = (bufc * 2 + 0) * 2048 + (wm * 128 + mh * 64 + mf * 16 + r16) * 8;
            af[mf][0] = L8[rb + x0];
            af[mf][1] = L8[rb + x1];
        }
    };
    auto rdB = [&](int bufc, int nh) {
#pragma unroll
        for (int nf = 0; nf < 2; ++nf) {
            int rb = (bufc * 2 + 1) * 2048 + (wn * 64 + nh * 32 + nf * 16 + r16) * 8;
            bfr[nh][nf][0] = L8[rb + x0];
            bfr[nh][nf][1] = L8[rb + x1];
        }
    };
    auto mmQ = [&](int mh, int nh) {
#pragma unroll
        for (int mf = 0; mf < 4; ++mf)
#pragma unroll
            for (int nf = 0; nf < 2; ++nf) {
                acc[mh*4+mf][nh*2+nf] = __builtin_amdgcn_mfma_f32_16x16x32_bf16(
                    af[mf][0], bfr[nh][nf][0], acc[mh*4+mf][nh*2+nf], 0, 0, 0);
                acc[mh*4+mf][nh*2+nf] = __builtin_amdgcn_mfma_f32_16x16x32_bf16(
                    af[mf][1], bfr[nh][nf][1], acc[mh*4+mf][nh*2+nf], 0, 0, 0);
            }
    };

#define G8_PH(mh, nh) do { G8_BAR; G8_LGKM;                      \
        __builtin_amdgcn_s_setprio(1); mmQ(mh, nh);              \
        __builtin_amdgcn_s_setprio(0); G8_SB; G8_BAR; G8_SB; } while (0)

    stA(0, 0, 0); stA(0, 0, 1);
    stB(0, 0, 0); stB(0, 0, 1);
    stB(1, 1, 0); stB(1, 1, 1);
    G8_VM4;
    G8_BAR; G8_SB;

    for (int i = 0; i < G8_NK / 2 - 1; ++i) {
        const int v1 = 2 * i + 1, u2 = 2 * i + 2, v2 = 2 * i + 3;
        rdA(0,0); rdB(0,0); stA(1, v1, 0);         G8_PH(0,0);
        rdB(0,1);           stA(1, v1, 1);         G8_PH(0,1);
        rdA(0,1);           stB(0, u2, 0);         G8_PH(1,0);
                            stB(0, u2, 1); G8_VM4; G8_PH(1,1);
        rdA(1,0); rdB(1,0); stA(0, u2, 0);         G8_PH(0,0);
        rdB(1,1);           stA(0, u2, 1);         G8_PH(0,1);
        rdA(1,1);           stB(1, v2, 0);         G8_PH(1,0);
                            stB(1, v2, 1); G8_VM4; G8_PH(1,1);
    }
    rdA(0,0); rdB(0,0); stA(1, G8_NK - 1, 0); G8_PH(0,0);
    rdB(0,1);           stA(1, G8_NK - 1, 1); G8_PH(0,1);
    rdA(0,1);                                 G8_PH(1,0);
                        G8_VM0;               G8_PH(1,1);
    rdA(1,0); rdB(1,0);                       G8_PH(0,0);
    rdB(1,1);                                 G8_PH(0,1);
    rdA(1,1);                                 G8_PH(1,0);
                                              G8_PH(1,1);

    bf16_t* Cb = C;
    int csub = 0;
    if (SPLIT && n0 >= 2048) { Cb = C2; csub = 2048; }

    float bv[4] = {0.f, 0.f, 0.f, 0.f};
    if (EPI >= 1) {
#pragma unroll
        for (int b = 0; b < 4; ++b) {
            int colg = n0 + wn * 64 + (b >> 1) * 32 + (b & 1) * 16 + r16;
            bv[b] = __bfloat162float(bias[colg]);
        }
    }
#pragma unroll
    for (int a = 0; a < 8; ++a) {
#pragma unroll
        for (int r = 0; r < 4; ++r) {
            int rowg = m0 + wm * 128 + (a >> 2) * 64 + (a & 3) * 16 + q * 4 + r;
#pragma unroll
            for (int b = 0; b < 4; ++b) {
                int colg = n0 + wn * 64 + (b >> 1) * 32 + (b & 1) * 16 + r16;
                float v = acc[a][b][r];
                if (EPI >= 1) v += bv[b];
                if (EPI == 2) v = v > 0.f ? v : 0.f;
                Cb[(size_t)rowg * ldc + (colg - csub)] = __float2bfloat16(v);
            }
        }
    }
#undef G8_PH
}

// ================== 8-phase 256x128 GEMM (narrow-N variant, r8 version) =======
template <int LDK, int NKT, int EPI, bool DYN>   // EPI: 0 none, 1 +bias
__global__ __launch_bounds__(512, 2)
void gemm8n(const bf16_t* __restrict__ A, const bf16_t* __restrict__ W,
            bf16_t* __restrict__ C, const bf16_t* __restrict__ bias, int ldc,
            const int* oflag, int c_row_off)
{
    __shared__ __align__(16) bf16_t ldsmem[2][24576];   // 49152 B per buf: A 32K | B 16K

    const int tid  = threadIdx.x;
    const int lane = tid & 63;
    const int wv   = tid >> 6;      // 0..7
    const int wm   = wv >> 2;       // 0..1 (128 rows)
    const int wn   = wv & 3;        // 0..3 (32 cols)
    const int r16  = lane & 15;
    const int q    = lane >> 4;
    const int m0   = blockIdx.x * 256;
    const int n0   = blockIdx.y * 128;

    const int x0 = q ^ (r16 & 7);
    const int x1 = (4 + q) ^ (r16 & 7);

    const int srow = tid >> 3;                       // 0..63
    const int scol = (tid & 7) ^ (srow & 7);
    const bf16_t* Abase = A + (size_t)(m0 + srow) * LDK + scol * 8;
    const bf16_t* Wbase = W + (size_t)(n0 + srow) * LDK + scol * 8;
    const int woff = wv * 1024;

    const bf16x8* L8 = (const bf16x8*)ldsmem;        // 16B chunk units
    char*         Lb = (char*)ldsmem;

    f32x4  acc[8][2] = {};
    bf16x8 af[4][2];          // [mf][kk]
    bf16x8 bfr[2][2];         // [nf][kk]

    auto stA = [&](int bufc, int tile, int half) {
        const bf16_t* g = Abase + (size_t)half * (128 * LDK) + tile * 64;
        char* l = Lb + (size_t)bufc * 49152 + half * 16384 + woff;
        gld_lds16(g, l);
        gld_lds16(g + (size_t)64 * LDK, l + 8192);
    };
    auto stB = [&](int bufc, int tile) {
        const bf16_t* g = Wbase + tile * 64;
        char* l = Lb + (size_t)bufc * 49152 + 32768 + woff;
        gld_lds16(g, l);
        gld_lds16(g + (size_t)64 * LDK, l + 8192);
    };
    auto rdA = [&](int bufc, int mh) {
#pragma unroll
        for (int mf = 0; mf < 4; ++mf) {
            int rb = bufc * 3072 + (wm * 128 + mh * 64 + mf * 16 + r16) * 8;
            af[mf][0] = L8[rb + x0];
            af[mf][1] = L8[rb + x1];
        }
    };
    auto rdB = [&](int bufc) {
#pragma unroll
        for (int nf = 0; nf < 2; ++nf) {
            int rb = bufc * 3072 + 2048 + (wn * 32 + nf * 16 + r16) * 8;
            bfr[nf][0] = L8[rb + x0];
            bfr[nf][1] = L8[rb + x1];
        }
    };
    auto mmP = [&](int mh) {
#pragma unroll
        for (int mf = 0; mf < 4; ++mf)
#pragma unroll
            for (int nf = 0; nf < 2; ++nf) {
                acc[mh*4+mf][nf] = __builtin_amdgcn_mfma_f32_16x16x32_bf16(
                    af[mf][0], bfr[nf][0], acc[mh*4+mf][nf], 0, 0, 0);
                acc[mh*4+mf][nf] = __builtin_amdgcn_mfma_f32_16x16x32_bf16(
                    af[mf][1], bfr[nf][1], acc[mh*4+mf][nf], 0, 0, 0);
            }
    };

#define GN_PH(mh) do { G8_BAR; G8_LGKM;                          \
        __builtin_amdgcn_s_setprio(1); mmP(mh);                  \
        __builtin_amdgcn_s_setprio(0); G8_SB; G8_BAR; G8_SB; } while (0)

    stA(0, 0, 0); stA(0, 0, 1);
    stB(0, 0);
    stB(1, 1);
    G8_VM2;
    G8_BAR; G8_SB;

    for (int i = 0; i < NKT / 2 - 1; ++i) {
        const int v1 = 2 * i + 1, u2 = 2 * i + 2, v2 = 2 * i + 3;
        rdA(0,0); rdB(0); stA(1, v1, 0); stA(1, v1, 1); GN_PH(0);   // P1
        rdA(0,1);         stB(0, u2); G8_VM2;           GN_PH(1);   // P2
        rdA(1,0); rdB(1); stA(0, u2, 0); stA(0, u2, 1); GN_PH(0);   // P3
        rdA(1,1);         stB(1, v2); G8_VM2;           GN_PH(1);   // P4
    }
    rdA(0,0); rdB(0); stA(1, NKT - 1, 0); stA(1, NKT - 1, 1); GN_PH(0);
    rdA(0,1);         G8_VM0;                                 GN_PH(1);
    rdA(1,0); rdB(1);                                         GN_PH(0);
    rdA(1,1);                                                 GN_PH(1);

    int of = 1;
    if constexpr (DYN) of = *oflag;
    float bv[2] = {0.f, 0.f};
    if (EPI >= 1) {
#pragma unroll
        for (int nf = 0; nf < 2; ++nf)
            bv[nf] = __bfloat162float(bias[n0 + wn * 32 + nf * 16 + r16]);
    }
#pragma unroll
    for (int a = 0; a < 8; ++a) {
#pragma unroll
        for (int r = 0; r < 4; ++r) {
            int rowg = m0 + wm * 128 + a * 16 + q * 4 + r;
#pragma unroll
            for (int nf = 0; nf < 2; ++nf) {
                int colg = n0 + wn * 32 + nf * 16 + r16;
                float v = acc[a][nf][r];
                if (EPI >= 1) v += bv[nf];
                if constexpr (DYN) {
                    size_t idx = (size_t)(c_row_off + rowg) * ldc + colg;
                    if (of) ((bf16_t*)C)[idx] = __float2bfloat16(v);
                    else    ((float*)C)[idx]  = v;
                } else {
                    C[(size_t)rowg * ldc + colg] = __float2bfloat16(v);
                }
            }
        }
    }
#undef GN_PH
}

// ---------- GEMM: 2-phase fallback for small/odd shapes ----------
#define TM 128
#define TN 128
#define TK 64

template <typename OutT, int EPI, bool DYN, bool EDGE>
__global__ __launch_bounds__(256, 2)
void gemm_bt(const bf16_t* __restrict__ A, int lda,
             const bf16_t* __restrict__ W, int ldw,
             OutT* __restrict__ C, int ldc,
             OutT* __restrict__ C2, int nsplit,
             const bf16_t* __restrict__ bias,
             int M, int N, int K,
             const int* oflag, int c_row_off)
{
    __shared__ bf16_t sA[TM * TK];
    __shared__ bf16_t sB[TN * TK];

    const int tid  = threadIdx.x;
    const int lane = tid & 63;
    const int wv   = tid >> 6;
    const int m0   = blockIdx.x * TM;
    const int n0   = blockIdx.y * TN;
    const int wm   = (wv >> 1) * 64;
    const int wn   = (wv & 1) * 64;
    const int r16  = lane & 15;
    const int q    = lane >> 4;

    int of = 1;
    if constexpr (DYN) of = *oflag;

    f32x4 acc[4][4] = {};

    for (int k0 = 0; k0 < K; k0 += TK) {
#pragma unroll
        for (int i = 0; i < 4; ++i) {
            int c    = (i * 4 + wv) * 64 + lane;
            int row  = c >> 3;
            int col8 = c & 7;
            const bf16_t* ga = A + (size_t)(m0 + row) * lda + k0 + col8 * 8;
            gld_lds16(ga, (char*)sA + (size_t)(i * 4 + wv) * 1024);
            int nrow = n0 + row;
            if (EDGE && nrow > N - 1) nrow = N - 1;
            const bf16_t* gb = W + (size_t)nrow * ldw + k0 + col8 * 8;
            gld_lds16(gb, (char*)sB + (size_t)(i * 4 + wv) * 1024);
        }
        __syncthreads();

        const bf16x8* sA8 = (const bf16x8*)sA;
        const bf16x8* sB8 = (const bf16x8*)sB;
#pragma unroll
        for (int kk = 0; kk < 2; ++kk) {
            bf16x8 af[4], bfr[4];
#pragma unroll
            for (int i = 0; i < 4; ++i)
                af[i] = sA8[(wm + i * 16 + r16) * 8 + kk * 4 + q];
#pragma unroll
            for (int j = 0; j < 4; ++j)
                bfr[j] = sB8[(wn + j * 16 + r16) * 8 + kk * 4 + q];
#pragma unroll
            for (int i = 0; i < 4; ++i)
#pragma unroll
                for (int j = 0; j < 4; ++j)
                    acc[i][j] = __builtin_amdgcn_mfma_f32_16x16x32_bf16(
                        af[i], bfr[j], acc[i][j], 0, 0, 0);
        }
        __syncthreads();
    }

    OutT* Cb = C;
    int csub = 0;
    if (C2 != nullptr && n0 >= nsplit) { Cb = C2; csub = nsplit; }

#pragma unroll
    for (int j = 0; j < 4; ++j) {
        int colg = n0 + wn + j * 16 + r16;
        if (EDGE && colg >= N) continue;
        float bv = 0.f;
        if (EPI >= 1) bv = __bfloat162float(bias[colg]);
#pragma unroll
        for (int i = 0; i < 4; ++i) {
#pragma unroll
            for (int r = 0; r < 4; ++r) {
                int rowg = m0 + wm + i * 16 + q * 4 + r;
                if (EDGE && rowg >= M) continue;
                float v = acc[i][j][r];
                if (EPI >= 1) v += bv;
                if (EPI == 2) v = v > 0.f ? v : 0.f;
                if (EPI == 3) v = (v > 20.f) ? v : log1pf(__expf(v));
                if constexpr (DYN) {
                    size_t idx = (size_t)(c_row_off + rowg) * ldc + colg;
                    if (of) ((bf16_t*)Cb)[idx] = __float2bfloat16(v);
                    else    ((float*)Cb)[idx]  = v;
                } else if constexpr (std::is_same<OutT, float>::value) {
                    Cb[(size_t)rowg * ldc + (colg - csub)] = v;
                } else {
                    Cb[(size_t)rowg * ldc + (colg - csub)] = __float2bfloat16(v);
                }
            }
        }
    }
}

// ---------- x_proj split-K GEMM ----------
__global__ __launch_bounds__(256, 2)
void gemm_xproj_splitk(const bf16_t* __restrict__ A,
                       const bf16_t* __restrict__ W,
                       float* __restrict__ part, int M)
{
    __shared__ bf16_t sA[TM * TK];
    __shared__ bf16_t sB[TN * TK];

    const int tid  = threadIdx.x;
    const int lane = tid & 63;
    const int wv   = tid >> 6;
    const int m0   = blockIdx.x * TM;
    const int kz   = blockIdx.z;
    const int wm   = (wv >> 1) * 64;
    const int wn   = (wv & 1) * 64;
    const int r16  = lane & 15;
    const int q    = lane >> 4;

    f32x4 acc[4][4] = {};

    const int kbeg = kz * (2048 / KS);
    for (int k0 = kbeg; k0 < kbeg + 2048 / KS; k0 += TK) {
#pragma unroll
        for (int i = 0; i < 4; ++i) {
            int c    = (i * 4 + wv) * 64 + lane;
            int row  = c >> 3;
            int col8 = c & 7;
            const bf16_t* ga = A + (size_t)(m0 + row) * DI + k0 + col8 * 8;
            gld_lds16(ga, (char*)sA + (size_t)(i * 4 + wv) * 1024);
            int nrow = row; if (nrow > 95) nrow = 95;
            const bf16_t* gb = W + (size_t)nrow * DI + k0 + col8 * 8;
            gld_lds16(gb, (char*)sB + (size_t)(i * 4 + wv) * 1024);
        }
        __syncthreads();

        const bf16x8* sA8 = (const bf16x8*)sA;
        const bf16x8* sB8 = (const bf16x8*)sB;
#pragma unroll
        for (int kk = 0; kk < 2; ++kk) {
            bf16x8 af[4], bfr[4];
#pragma unroll
            for (int i = 0; i < 4; ++i)
                af[i] = sA8[(wm + i * 16 + r16) * 8 + kk * 4 + q];
#pragma unroll
            for (int j = 0; j < 4; ++j)
                bfr[j] = sB8[(wn + j * 16 + r16) * 8 + kk * 4 + q];
#pragma unroll
            for (int i = 0; i < 4; ++i)
#pragma unroll
                for (int j = 0; j < 4; ++j)
                    acc[i][j] = __builtin_amdgcn_mfma_f32_16x16x32_bf16(
                        af[i], bfr[j], acc[i][j], 0, 0, 0);
        }
        __syncthreads();
    }

#pragma unroll
    for (int j = 0; j < 4; ++j) {
        int colg = wn + j * 16 + r16;
        if (colg >= 96) continue;
#pragma unroll
        for (int i = 0; i < 4; ++i) {
#pragma unroll
            for (int r = 0; r < 4; ++r) {
                int rowg = m0 + wm + i * 16 + q * 4 + r;
                part[((size_t)kz * M + rowg) * 96 + colg] = acc[i][j][r];
            }
        }
    }
}

__global__ __launch_bounds__(256)
void xproj_reduce(const float* __restrict__ part, bf16_t* __restrict__ xdbl,
                  float* __restrict__ x32, int M)
{
    int i = blockIdx.x * 256 + threadIdx.x;
    int n = M * 96;
    if (i >= n) return;
    float s = part[i] + part[(size_t)n + i] + part[2 * (size_t)n + i] + part[3 * (size_t)n + i];
    xdbl[i] = __float2bfloat16(s);
    if (x32) x32[i] = s;
}

// ---------- depthwise causal conv (k=4) + bias + SiLU ----------
__global__ __launch_bounds__(256)
void conv_silu_kernel(const bf16_t* __restrict__ u,
                      const bf16_t* __restrict__ cw,
                      const bf16_t* __restrict__ cb,
                      bf16_t* __restrict__ uc,
                      int Mrows)
{
    int idx = blockIdx.x * 256 + threadIdx.x;
    int eg  = idx & 255;
    int row = idx >> 8;
    if (row >= Mrows) return;
    int t = row & (LL - 1);
    int b = row >> 11;
    int e0 = eg * 8;

    float wf[32];
    {
        const uint4* wp = (const uint4*)(cw + (size_t)e0 * 4);
        uint4 w0 = wp[0], w1 = wp[1], w2 = wp[2], w3 = wp[3];
        unpack8(w0, wf); unpack8(w1, wf + 8); unpack8(w2, wf + 16); unpack8(w3, wf + 24);
    }
    float bias[8];
    unpack8(*(const uint4*)(cb + e0), bias);

    float uk[4][8];
#pragma unroll
    for (int k = 0; k < 4; ++k) {
        int tt = t - 3 + k;
        if (tt >= 0) {
            uint4 uv = *(const uint4*)(u + (size_t)(b * LL + tt) * DI + e0);
            unpack8(uv, uk[k]);
        } else {
#pragma unroll
            for (int j = 0; j < 8; ++j) uk[k][j] = 0.f;
        }
    }
    bf16_t out8[8];
#pragma unroll
    for (int j = 0; j < 8; ++j) {
        float a = bias[j];
#pragma unroll
        for (int k = 0; k < 4; ++k) a += wf[j * 4 + k] * uk[k][j];
        a = a / (1.f + __expf(-a));
        out8[j] = __float2bfloat16(a);
    }
    *(uint4*)(uc + (size_t)row * DI + e0) = *(uint4*)out8;
}

// ---------- chunked parallel scan: LDS-staged tiles, counted-vmcnt pipeline ---
__global__ __launch_bounds__(256, 4)
void scan_pass1(const bf16_t* __restrict__ uc, const bf16_t* __restrict__ dtb,
                const float* __restrict__ x32, const bf16_t* __restrict__ A_log,
                float* __restrict__ hfin, float* __restrict__ Ssum, int lgG)
{
    __shared__ __align__(16) char sm1[36864];   // U[2] 0/8K, D[2] 16/24K, B 32K..36K
    const int tid  = threadIdx.x;
    const int lane = tid & 63;
    const int wv   = tid >> 6;
    const int bid  = blockIdx.x;
    const int eb   = bid & 7;
    const int rem  = bid >> 3;
    const int b    = rem & ((1 << lgG) - 1);
    const int chunk = rem >> lgG;
    const int e0   = eb * 256;
    const int e    = e0 + tid;
    const int t0   = chunk * CL;

    const bf16_t* ub = uc  + (size_t)(b * LL + t0) * DI;
    const bf16_t* db = dtb + (size_t)(b * LL + t0) * DI;
    const float*  xr = x32 + (size_t)(b * LL + t0) * 96 + 64;

    char* const U[2] = { sm1, sm1 + 8192 };
    char* const D[2] = { sm1 + 16384, sm1 + 24576 };
    char* const Bl   = sm1 + 32768;

    auto stage2 = [&](const bf16_t* src, char* dst, int trow0) {
        const int c8 = (lane & 31) * 8;
        const int r0 = 2 * wv + (lane >> 5);
        gld_lds16(src + (size_t)(trow0 + r0) * DI + e0 + c8, dst + wv * 1024 + lane * 16);
        gld_lds16(src + (size_t)(trow0 + r0 + 8) * DI + e0 + c8, dst + (wv + 4) * 1024 + lane * 16);
    };
    // stage whole chunk's B panel (64 steps x 64B): 256 chunks of 16B, 1/thread
    {
        int s = tid >> 2, p = tid & 3;
        gld_lds16(xr + (size_t)s * 96 + p * 4, Bl + tid * 16);      // 1 op
    }
    stage2(ub, U[0], 0);  stage2(db, D[0], 0);                      // 4 ops
    stage2(ub, U[1], TT); stage2(db, D[1], TT);                     // 4 ops

    // prologue (covers staging latency): 16 exps
    float alf[16];
    {
        uint4 v0 = *(const uint4*)(A_log + (size_t)e * NS);
        uint4 v1 = *(const uint4*)(A_log + (size_t)e * NS + 8);
        unpack8(v0, alf); unpack8(v1, alf + 8);
    }
    float a0 = -__expf(alf[0]) * LOG2E;
    float Aa2[16];
    int fast = 1;
#pragma unroll
    for (int n = 0; n < 16; ++n) {
        Aa2[n] = -__expf(alf[n]) * LOG2E;
        float ideal = (float)(n + 1) * a0;
        fast = fast && (fabsf(Aa2[n] - ideal) <= 0.02f * fabsf(ideal));
    }
    int allfast = __syncthreads_and(fast);

    float h[16];
#pragma unroll
    for (int j = 0; j < 16; ++j) h[j] = 0.f;
    float Ss = 0.f;

#define P1_CMP(K, FAST) do {                                                  \
        const char* Ut = U[(K) & 1]; const char* Dt = D[(K) & 1];             \
        _Pragma("unroll")                                                     \
        for (int t = 0; t < TT; ++t) {                                        \
            float cu  = __bfloat162float(*(const bf16_t*)(Ut + t * 512 + tid * 2)); \
            float cdt = __bfloat162float(*(const bf16_t*)(Dt + t * 512 + tid * 2)); \
            const float* bc = (const float*)(Bl + ((K) * TT + t) * 64);       \
            float du = cdt * cu; Ss += cdt;                                   \
            if (FAST) {                                                       \
                float r = EXP2F(cdt * a0);                                    \
                float r2 = r * r, r4 = r2 * r2, r8 = r4 * r4;                 \
                float dA = r, dB = r8 * r;                                    \
                _Pragma("unroll")                                             \
                for (int j = 0; j < 8; ++j) { h[j] = dA * h[j] + du * bc[j]; dA *= r; } \
                _Pragma("unroll")                                             \
                for (int j = 8; j < 16; ++j) { h[j] = dB * h[j] + du * bc[j]; dB *= r; } \
            } else {                                                          \
                _Pragma("unroll")                                             \
                for (int j = 0; j < 16; ++j) {                                \
                    float dA = EXP2F(cdt * Aa2[j]);                           \
                    h[j] = dA * h[j] + du * bc[j]; }                          \
            }                                                                 \
        } } while (0)

#define P1_SEQ(FAST) do {                                                     \
        G8_VM4; G8_BAR; G8_SB;                                                \
        P1_CMP(0, FAST); G8_LGKM; G8_BAR; G8_SB;                              \
        stage2(ub, U[0], 2 * TT); stage2(db, D[0], 2 * TT);                   \
        G8_VM4; G8_BAR; G8_SB;                                                \
        P1_CMP(1, FAST); G8_LGKM; G8_BAR; G8_SB;                              \
        stage2(ub, U[1], 3 * TT); stage2(db, D[1], 3 * TT);                   \
        G8_VM4; G8_BAR; G8_SB;                                                \
        P1_CMP(2, FAST); G8_LGKM; G8_BAR; G8_SB;                              \
        G8_VM0; G8_BAR; G8_SB;                                                \
        P1_CMP(3, FAST);                                                      \
    } while (0)

    if (allfast) P1_SEQ(true); else P1_SEQ(false);
#undef P1_SEQ
#undef P1_CMP

    size_t base = (size_t)(b * NC + chunk) * NS * DI + e;
#pragma unroll
    for (int j = 0; j < 16; ++j) hfin[base + (size_t)j * DI] = h[j];
    Ssum[(size_t)(b * NC + chunk) * DI + e] = Ss;
}

__global__ __launch_bounds__(256)
void scan_pass2(const float* __restrict__ Ssum, const bf16_t* __restrict__ A_log,
                float* __restrict__ hfin)
{
    int idx = blockIdx.x * 256 + threadIdx.x;
    int e = idx & (DI - 1);
    int rem = idx >> 11;
    int n = rem & (NS - 1);
    int b = rem >> 4;
    float Aa2 = -__expf(__bfloat162float(A_log[(size_t)e * NS + n])) * LOG2E;
    float h = 0.f;
    for (int c = 0; c < NC; ++c) {
        size_t a = ((size_t)(b * NC + c) * NS + n) * DI + e;
        float S  = Ssum[(size_t)(b * NC + c) * DI + e];
        float hf = hfin[a];
        hfin[a] = h;
        h = EXP2F(Aa2 * S) * h + hf;
    }
}

__global__ __launch_bounds__(256, 2)
void scan_pass3(const bf16_t* __restrict__ uc, const bf16_t* __restrict__ dtb,
                const float* __restrict__ x32, bf16_t* __restrict__ zy,
                const bf16_t* __restrict__ A_log, const bf16_t* __restrict__ Dp,
                const float* __restrict__ hin, int lgG)
{
    __shared__ __align__(16) char sm3[65536];  // U 0/8K, D 16/24K, Z 32/40K, Y 48K, BC 56K
    const int tid  = threadIdx.x;
    const int lane = tid & 63;
    const int wv   = tid >> 6;
    const int bid  = blockIdx.x;
    const int eb   = bid & 7;
    const int rem  = bid >> 3;
    const int b    = rem & ((1 << lgG) - 1);
    const int chunk = rem >> lgG;
    const int e0   = eb * 256;
    const int e    = e0 + tid;
    const int t0   = chunk * CL;

    const bf16_t* ub = uc  + (size_t)(b * LL + t0) * DI;
    const bf16_t* db = dtb + (size_t)(b * LL + t0) * DI;
    bf16_t*       zb = zy  + (size_t)(b * LL + t0) * DI;   // z in, y out
    const float*  xr = x32 + (size_t)(b * LL + t0) * 96 + 64;

    char* const U[2] = { sm3, sm3 + 8192 };
    char* const D[2] = { sm3 + 16384, sm3 + 24576 };
    char* const Z[2] = { sm3 + 32768, sm3 + 40960 };
    char* const Y    = sm3 + 49152;
    char* const BC   = sm3 + 57344;

    auto stage2 = [&](const bf16_t* src, char* dst, int trow0) {
        const int c8 = (lane & 31) * 8;
        const int r0 = 2 * wv + (lane >> 5);
        gld_lds16(src + (size_t)(trow0 + r0) * DI + e0 + c8, dst + wv * 1024 + lane * 16);
        gld_lds16(src + (size_t)(trow0 + r0 + 8) * DI + e0 + c8, dst + (wv + 4) * 1024 + lane * 16);
    };
    // stage whole chunk's B+C panel (64 steps x 128B = 8KB): 512 chunks, 2/thread
    {
        int s1 = tid >> 3, p1 = tid & 7;
        gld_lds16(xr + (size_t)s1 * 96 + p1 * 4, BC + tid * 16);
        gld_lds16(xr + (size_t)(s1 + 32) * 96 + p1 * 4, BC + 4096 + tid * 16);
    }                                                                // 2 ops
    stage2(ub, U[0], 0);  stage2(db, D[0], 0);  stage2(zb, Z[0], 0);   // 6
    stage2(ub, U[1], TT); stage2(db, D[1], TT); stage2(zb, Z[1], TT);  // 6

    // prologue (covers staging latency)
    float alf[16];
    {
        uint4 v0 = *(const uint4*)(A_log + (size_t)e * NS);
        uint4 v1 = *(const uint4*)(A_log + (size_t)e * NS + 8);
        unpack8(v0, alf); unpack8(v1, alf + 8);
    }
    float a0 = -__expf(alf[0]) * LOG2E;
    float Aa2[16];
    int fast = 1;
#pragma unroll
    for (int n = 0; n < 16; ++n) {
        Aa2[n] = -__expf(alf[n]) * LOG2E;
        float ideal = (float)(n + 1) * a0;
        fast = fast && (fabsf(Aa2[n] - ideal) <= 0.02f * fabsf(ideal));
    }
    int allfast = __syncthreads_and(fast);

    float Dv = __bfloat162float(Dp[e]);
    size_t hbase = (size_t)(b * NC + chunk) * NS * DI + e;
    float h[16];
#pragma unroll
    for (int j = 0; j < 16; ++j) h[j] = hin[hbase + (size_t)j * DI];

    auto yflush = [&](int K) {
        const int r0 = tid >> 5;
        const int c  = (tid & 31) * 16;
        uint4 v0 = *(const uint4*)(Y + r0 * 512 + c);
        uint4 v1 = *(const uint4*)(Y + (r0 + 8) * 512 + c);
        *(uint4*)(zb + (size_t)(K * TT + r0) * DI + e0 + (tid & 31) * 8)     = v0;
        *(uint4*)(zb + (size_t)(K * TT + r0 + 8) * DI + e0 + (tid & 31) * 8) = v1;
    };

#define P3_CMP(K, FAST) do {                                                  \
        const char* Ut = U[(K) & 1]; const char* Dt = D[(K) & 1];             \
        const char* Zt = Z[(K) & 1];                                          \
        _Pragma("unroll")                                                     \
        for (int t = 0; t < TT; ++t) {                                        \
            float cu  = __bfloat162float(*(const bf16_t*)(Ut + t * 512 + tid * 2)); \
            float cdt = __bfloat162float(*(const bf16_t*)(Dt + t * 512 + tid * 2)); \
            float cz  = __bfloat162float(*(const bf16_t*)(Zt + t * 512 + tid * 2)); \
            const float* bc = (const float*)(BC + ((K) * TT + t) * 128);      \
            float du = cdt * cu;                                              \
            if (FAST) {                                                       \
                float r = EXP2F(cdt * a0);                                    \
                float r2 = r * r, r4 = r2 * r2, r8 = r4 * r4;                 \
                float dA = r, dB = r8 * r;                                    \
                _Pragma("unroll")                                             \
                for (int j = 0; j < 8; ++j) { h[j] = dA * h[j] + du * bc[j]; dA *= r; } \
                _Pragma("unroll")                                             \
                for (int j = 8; j < 16; ++j) { h[j] = dB * h[j] + du * bc[j]; dB *= r; } \
            } else {                                                          \
                _Pragma("unroll")                                             \
                for (int j = 0; j < 16; ++j) {                                \
                    float dA = EXP2F(cdt * Aa2[j]);                           \
                    h[j] = dA * h[j] + du * bc[j]; }                          \
            }                                                                 \
            float y1 = 0.f, y2 = 0.f;                                         \
            _Pragma("unroll")                                                 \
            for (int j = 0; j < 8; ++j)  y1 += h[j] * bc[16 + j];             \
            _Pragma("unroll")                                                 \
            for (int j = 8; j < 16; ++j) y2 += h[j] * bc[16 + j];             \
            float yv  = y1 + y2;                                              \
            float sil = cz / (1.f + __expf(-cz));                             \
            *(bf16_t*)(Y + t * 512 + tid * 2) =                               \
                __float2bfloat16((yv + cu * Dv) * sil);                       \
        } } while (0)

#define P3_SEQ(FAST) do {                                                     \
        G8_VM6; G8_BAR; G8_SB;                                                \
        P3_CMP(0, FAST); G8_LGKM; G8_BAR; G8_SB;                              \
        yflush(0);                                                            \
        stage2(ub, U[0], 2*TT); stage2(db, D[0], 2*TT); stage2(zb, Z[0], 2*TT); \
        G8_VM8; G8_BAR; G8_SB;                                                \
        P3_CMP(1, FAST); G8_LGKM; G8_BAR; G8_SB;                              \
        yflush(1);                                                            \
        stage2(ub, U[1], 3*TT); stage2(db, D[1], 3*TT); stage2(zb, Z[1], 3*TT); \
        G8_VM8; G8_BAR; G8_SB;                                                \
        P3_CMP(2, FAST); G8_LGKM; G8_BAR; G8_SB;                              \
        yflush(2);                                                            \
        G8_VM2; G8_BAR; G8_SB;                                                \
        P3_CMP(3, FAST); G8_LGKM; G8_BAR; G8_SB;                              \
        yflush(3);                                                            \
    } while (0)

    if (allfast) P3_SEQ(true); else P3_SEQ(false);
#undef P3_SEQ
#undef P3_CMP
}

// ---------- serial scan fallback (reads bf16 xdbl) ----------
__global__ __launch_bounds__(64)
void scan_kernel(const bf16_t* __restrict__ uc,
                 const bf16_t* __restrict__ dt,
                 const bf16_t* __restrict__ xdbl,
                 bf16_t* __restrict__ zy,
                 const bf16_t* __restrict__ A_log,
                 const bf16_t* __restrict__ Dp)
{
    int idx = blockIdx.x * 64 + threadIdx.x;
    int e = idx & (DI - 1);
    int b = idx >> 11;

    float Aa[NS];
#pragma unroll
    for (int n = 0; n < NS; ++n)
        Aa[n] = -__expf(__bfloat162float(A_log[e * NS + n]));
    float Dv = __bfloat162float(Dp[e]);
    float h[NS];
#pragma unroll
    for (int n = 0; n < NS; ++n) h[n] = 0.f;

    const bf16_t* up  = uc   + (size_t)b * LL * DI + e;
    const bf16_t* dp  = dt   + (size_t)b * LL * DI + e;
    const bf16_t* zp  = zy   + (size_t)b * LL * DI + e;
    const bf16_t* bcp = xdbl + (size_t)b * LL * 96 + 64;
    bf16_t*       yp  = zy   + (size_t)b * LL * DI + e;

    float nu  = __bfloat162float(*up);
    float ndt = __bfloat162float(*dp);
    float nz  = __bfloat162float(*zp);
    uint4 nb0 = *(const uint4*)(bcp);
    uint4 nb1 = *(const uint4*)(bcp + 8);
    uint4 nc0 = *(const uint4*)(bcp + 16);
    uint4 nc1 = *(const uint4*)(bcp + 24);

    for (int t = 0; t < LL; ++t) {
        float cu = nu, cdt = ndt, cz = nz;
        uint4 b0 = nb0, b1 = nb1, c0 = nc0, c1 = nc1;
        if (t + 1 < LL) {
            up += DI; dp += DI; zp += DI; bcp += 96;
            nu  = __bfloat162float(*up);
            ndt = __bfloat162float(*dp);
            nz  = __bfloat162float(*zp);
            nb0 = *(const uint4*)(bcp);
            nb1 = *(const uint4*)(bcp + 8);
            nc0 = *(const uint4*)(bcp + 16);
            nc1 = *(const uint4*)(bcp + 24);
        }
        float Bv[NS], Cv[NS];
        unpack8(b0, Bv); unpack8(b1, Bv + 8);
        unpack8(c0, Cv); unpack8(c1, Cv + 8);

        float du = cdt * cu;
        float yv = 0.f;
#pragma unroll
        for (int n = 0; n < NS; ++n) {
            float dA = __expf(cdt * Aa[n]);
            h[n] = dA * h[n] + du * Bv[n];
            yv += h[n] * Cv[n];
        }
        float sil  = cz / (1.f + __expf(-cz));
        float outv = (yv + cu * Dv) * sil;
        *yp = __float2bfloat16(outv);
        yp += DI;
    }
}

// ---------- launcher ----------
extern "C" void kernel_launch(void* const* d_in, const int* in_sizes, int n_in,
                              void* d_out, int out_size, void* d_ws, size_t ws_size,
                              hipStream_t stream)
{
    char* ws = (char*)d_ws;
    int* flag = (int*)ws;
    size_t cur = 256;
    auto alloc = [&](size_t bytes) { bf16_t* p = (bf16_t*)(ws + cur); cur += bytes; return p; };

    const size_t o_xb = cur;
    bf16_t* xb   = alloc((size_t)MTOK * DM * 2);      // 16 MiB
    bf16_t* w_in = alloc((size_t)2 * DI * DM * 2);    //  8 MiB
    bf16_t* w_o  = alloc((size_t)DM * DI * 2);
    bf16_t* w_l1 = alloc((size_t)DFF * DM * 2);
    bf16_t* w_l2 = alloc((size_t)DM * DFF * 2);
    bf16_t* w_xp = alloc((size_t)96 * DI * 2);
    bf16_t* w_dt = alloc((size_t)DI * DTR * 2);
    bf16_t* cw   = alloc((size_t)DI * 4 * 2);
    bf16_t* cb   = alloc((size_t)DI * 2);
    bf16_t* dpb  = alloc((size_t)DI * 2);
    bf16_t* alog = alloc((size_t)DI * NS * 2);
    bf16_t* dd   = alloc((size_t)DI * 2);
    bf16_t* l1b  = alloc((size_t)DFF * 2);
    bf16_t* l2b  = alloc((size_t)DM * 2 + 2048);
    cur = (cur + 255) & ~(size_t)255;
    const size_t o_pipe = cur;

    detect_dtype_kernel<<<1, 256, 0, stream>>>((const unsigned*)d_in[0], flag);

    {
        CvtDesc d;
        const void* ss[14] = { d_in[0], d_in[1], d_in[9], d_in[10], d_in[12], d_in[4],
                               d_in[5], d_in[2], d_in[3], d_in[6], d_in[7], d_in[8],
                               d_in[11], d_in[13] };
        bf16_t* dd_[14]    = { xb, w_in, w_o, w_l1, w_l2, w_xp,
                               w_dt, cw, cb, dpb, alog, dd, l1b, l2b };
        size_t  nn[14]     = { (size_t)MTOK*DM, (size_t)2*DI*DM, (size_t)DM*DI,
                               (size_t)DFF*DM, (size_t)DM*DFF, (size_t)96*DI,
                               (size_t)DI*DTR, (size_t)DI*4, (size_t)DI, (size_t)DI,
                               (size_t)DI*NS, (size_t)DI, (size_t)DFF, (size_t)DM };
        int c = 0; d.cum[0] = 0;
        for (int i = 0; i < 14; ++i) {
            d.src[i] = ss[i]; d.dst[i] = dd_[i];
            c += (int)(nn[i] / 8); d.cum[i + 1] = c;
        }
        convert_all<<<(c + 255) / 256, 256, 0, stream>>>(d, flag, c);
    }

    auto pipe = [&](int Gq) { return (size_t)Gq * LL * 96 * 2 + 3ull * Gq * LL * DI * 2; };
    auto scr  = [&](int Gq) {
        return (size_t)Gq * NC * NS * DI * 4 + (size_t)Gq * NC * DI * 4 + (size_t)Gq * LL * 96 * 4;
    };

    int G; bool chunked; size_t scr_off;
    if      (ws_size >= o_pipe + pipe(4))            { G = 4; chunked = true;  scr_off = o_xb; }
    else if (ws_size >= o_pipe + pipe(2) + scr(2))   { G = 2; chunked = true;  scr_off = o_pipe + pipe(2); }
    else if (ws_size >= o_pipe + pipe(1) + scr(1))   { G = 1; chunked = true;  scr_off = o_pipe + pipe(1); }
    else                                             { G = 1; chunked = false; scr_off = o_pipe + pipe(1); }
    const int lgG = (G == 4) ? 2 : (G == 2 ? 1 : 0);

    const size_t hfin_sz = (size_t)G * NC * NS * DI * 4;
    const size_t ssum_sz = (size_t)G * NC * DI * 4;

    for (int g0 = 0; g0 < BB; g0 += G) {
        const int    Mg      = G * LL;
        const size_t xdbl_sz = (size_t)Mg * 96 * 2;
        const size_t big     = (size_t)Mg * DI * 2;

        bf16_t* xdbl = (bf16_t*)(ws + o_pipe);
        bf16_t* ubuf = (bf16_t*)(ws + o_pipe + xdbl_sz);
        bf16_t* dtb  = ubuf;
        bf16_t* zbuf = (bf16_t*)(ws + o_pipe + xdbl_sz + big);
        bf16_t* uc   = (bf16_t*)(ws + o_pipe + xdbl_sz + 2 * big);
        bf16_t* my   = uc;
        bf16_t* hh   = (bf16_t*)(ws + o_pipe);
        float*  xpp  = (float*)(ws + scr_off);
        float*  x32  = chunked ? (float*)(ws + scr_off + hfin_sz + ssum_sz) : nullptr;

        const bf16_t* x_g = xb + (size_t)g0 * LL * DM;

        dim3 blk(256);
        const int gx = Mg / TM;

        // 1. in_proj merged (N=4096, K=1024): 8-phase 256^2; cols<2048 -> ubuf, else zbuf
        gemm8<0, true><<<dim3(Mg / 256, 16), 512, 0, stream>>>(
            x_g, w_in, ubuf, zbuf, nullptr, DI);
        // 2. depthwise conv + SiLU -> uc
        conv_silu_kernel<<<Mg, 256, 0, stream>>>(ubuf, cw, cb, uc, Mg);
        // 3. x_proj split-K -> partials -> xdbl (bf16) + x32 (fp32)
        gemm_xproj_splitk<<<dim3(gx, 1, KS), blk, 0, stream>>>(uc, w_xp, xpp, Mg);
        xproj_reduce<<<(Mg * 96 + 255) / 256, 256, 0, stream>>>(xpp, xdbl, x32, Mg);
        // 4. dt_proj + softplus -> dtb
        gemm_bt<bf16_t, 3, false, false><<<dim3(gx, DI / TN), blk, 0, stream>>>(
            xdbl, 96, w_dt, DTR, dtb, DI, nullptr, 0, dpb, Mg, DI, DTR, nullptr, 0);
        // 5. selective scan + gating; y overwrites zbuf (LDS-staged tiles)
        if (chunked) {
            float* hfin = (float*)(ws + scr_off);
            float* Ssum = (float*)(ws + scr_off + hfin_sz);
            scan_pass1<<<G * NC * (DI / 256), 256, 0, stream>>>(uc, dtb, x32, alog, hfin, Ssum, lgG);
            scan_pass2<<<G * (NS * DI / 256), 256, 0, stream>>>(Ssum, alog, hfin);
            scan_pass3<<<G * NC * (DI / 256), 256, 0, stream>>>(uc, dtb, x32, zbuf, alog, dd, hfin, lgG);
        } else {
            scan_kernel<<<(G * DI) / 64, 64, 0, stream>>>(uc, dtb, xdbl, zbuf, alog, dd);
        }
        // 6. out_proj -> my (8-phase 256x128, K=2048)
        gemm8n<2048, 32, 0, false><<<dim3(Mg / 256, DM / 128), 512, 0, stream>>>(
            zbuf, w_o, my, nullptr, DM, nullptr, 0);
        // 7. lin1 + bias + relu -> hh (8-phase 256^2)
        gemm8<2, false><<<dim3(Mg / 256, 16), 512, 0, stream>>>(
            my, w_l1, hh, nullptr, l1b, DFF);
        // 8. lin2 + bias -> d_out (8-phase 256x128, K=4096, dtype per flag)
        gemm8n<4096, 64, 1, true><<<dim3(Mg / 256, DM / 128), 512, 0, stream>>>(
            hh, w_l2, (bf16_t*)d_out, l2b, DM, (const int*)ws, g0 * LL);
    }
}

// Round 11
// 559.451 us; speedup vs baseline: 1.2150x; 1.0535x over previous
//
#include <hip/hip_runtime.h>
#include <hip/hip_bf16.h>
#include <type_traits>
#include <math.h>

typedef __hip_bfloat16 bf16_t;

// Problem constants
#define BB 4
#define LL 2048
#define DM 1024
#define DI 2048
#define NS 16
#define DTR 64
#define DFF 4096
#define MTOK (BB*LL)   // 8192
#define NC 32          // scan chunks
#define CL (LL/NC)     // 64 timesteps per chunk
#define TT 16          // scan LDS tile (timesteps); CL/TT = 4 tiles
#define KS 4           // x_proj split-K factor

// raw 2^x (saves the log2e mul inside __expf; arg pre-scaled by caller)
#if defined(__has_builtin)
#if __has_builtin(__builtin_amdgcn_exp2f)
#define EXP2F(x) __builtin_amdgcn_exp2f(x)
#endif
#endif
#ifndef EXP2F
#define EXP2F(x) exp2f(x)
#endif
#define LOG2E 1.44269504088896340736f

// fast stable softplus: max(x,0) + log(1+exp(-|x|)); libm log1pf cost ~100 instr
// (r10: dt_proj 78us at 70% VALUBusy, MfmaUtil 1%) -> 2 HW transcendentals.
__device__ __forceinline__ float softplus_fast(float x) {
    return fmaxf(x, 0.f) + __logf(1.f + __expf(-fabsf(x)));
}

// ---------- helpers ----------
__device__ __forceinline__ float b2f_lo(unsigned u) {
    union { unsigned x; float f; } c; c.x = u << 16; return c.f;
}
__device__ __forceinline__ float b2f_hi(unsigned u) {
    union { unsigned x; float f; } c; c.x = u & 0xffff0000u; return c.f;
}
__device__ __forceinline__ void unpack8(uint4 v, float* o) {
    o[0] = b2f_lo(v.x); o[1] = b2f_hi(v.x);
    o[2] = b2f_lo(v.y); o[3] = b2f_hi(v.y);
    o[4] = b2f_lo(v.z); o[5] = b2f_hi(v.z);
    o[6] = b2f_lo(v.w); o[7] = b2f_hi(v.w);
}

typedef __attribute__((ext_vector_type(8))) short bf16x8;
typedef __attribute__((ext_vector_type(4))) float f32x4;

__device__ __forceinline__ void gld_lds16(const void* g, void* l) {
    __builtin_amdgcn_global_load_lds(
        (const __attribute__((address_space(1))) void*)g,
        (__attribute__((address_space(3))) void*)l, 16, 0, 0);
}

// shared scheduling macros
#define G8_BAR  __builtin_amdgcn_s_barrier()
#define G8_SB   __builtin_amdgcn_sched_barrier(0)
#define G8_LGKM do { asm volatile("s_waitcnt lgkmcnt(0)" ::: "memory"); G8_SB; } while (0)
#define G8_VM8  do { asm volatile("s_waitcnt vmcnt(8)"   ::: "memory"); G8_SB; } while (0)
#define G8_VM6  do { asm volatile("s_waitcnt vmcnt(6)"   ::: "memory"); G8_SB; } while (0)
#define G8_VM4  do { asm volatile("s_waitcnt vmcnt(4)"   ::: "memory"); G8_SB; } while (0)
#define G8_VM2  do { asm volatile("s_waitcnt vmcnt(2)"   ::: "memory"); G8_SB; } while (0)
#define G8_VM0  do { asm volatile("s_waitcnt vmcnt(0)"   ::: "memory"); G8_SB; } while (0)

// ---------- dtype detection (bf16 vs fp32 input buffers) ----------
__global__ void detect_dtype_kernel(const unsigned* __restrict__ x, int* __restrict__ flag)
{
    __shared__ int cnt;
    if (threadIdx.x == 0) cnt = 0;
    __syncthreads();
    int c = 0;
    for (int i = threadIdx.x; i < 4096; i += 256) {
        unsigned w = x[i];
        int e = (w >> 7) & 0xFF;
        c += (e >= 100 && e <= 140) ? 1 : 0;
    }
    atomicAdd(&cnt, c);
    __syncthreads();
    if (threadIdx.x == 0) *flag = (cnt > 2048) ? 1 : 0;
}

// ---------- canonicalize ALL inputs to bf16 in ONE launch ----------
struct CvtDesc {
    const void* src[14];
    bf16_t*     dst[14];
    int         cum[15];
};

__global__ __launch_bounds__(256)
void convert_all(CvtDesc d, const int* __restrict__ flag, int total8)
{
    int i = blockIdx.x * 256 + threadIdx.x;
    if (i >= total8) return;
    int t = 0;
#pragma unroll 1
    while (i >= d.cum[t + 1]) ++t;
    int j = i - d.cum[t];
    if (*flag) {
        ((uint4*)d.dst[t])[j] = ((const uint4*)d.src[t])[j];
    } else {
        const float4* s = (const float4*)d.src[t] + (size_t)j * 2;
        float4 a = s[0], b = s[1];
        bf16_t o[8];
        o[0] = __float2bfloat16(a.x); o[1] = __float2bfloat16(a.y);
        o[2] = __float2bfloat16(a.z); o[3] = __float2bfloat16(a.w);
        o[4] = __float2bfloat16(b.x); o[5] = __float2bfloat16(b.y);
        o[6] = __float2bfloat16(b.z); o[7] = __float2bfloat16(b.w);
        ((uint4*)d.dst[t])[j] = *(uint4*)o;
    }
}

// ================== 8-phase 256x256 GEMM (HK-style schedule) ==================
// r10-validated: natural block order (no XCD remap), direct stores with
// column-groups innermost (64B lines assemble before eviction).
#define G8_NK 16

template <int EPI, bool SPLIT>   // EPI: 0 none, 2 bias+relu
__global__ __launch_bounds__(512, 2)
void gemm8(const bf16_t* __restrict__ A, const bf16_t* __restrict__ W,
           bf16_t* __restrict__ C, bf16_t* __restrict__ C2,
           const bf16_t* __restrict__ bias, int ldc)
{
    __shared__ __align__(16) bf16_t ldsmem[2][2][256 * 64]; // [buf][op 0=A,1=B]

    const int tid  = threadIdx.x;
    const int lane = tid & 63;
    const int wv   = tid >> 6;      // 0..7
    const int wm   = wv >> 2;       // 0..1
    const int wn   = wv & 3;        // 0..3
    const int r16  = lane & 15;
    const int q    = lane >> 4;
    const int m0   = blockIdx.x * 256;
    const int n0   = blockIdx.y * 256;

    const int x0 = q ^ (r16 & 7);          // swizzled chunk idx, kk=0
    const int x1 = (4 + q) ^ (r16 & 7);    // kk=1

    const int srow = tid >> 3;                       // 0..63
    const int scol = (tid & 7) ^ (srow & 7);
    const bf16_t* Abase = A + (size_t)(m0 + srow) * 1024 + scol * 8;
    const bf16_t* Wbase = W + (size_t)(n0 + srow) * 1024 + scol * 8;
    const int woff = wv * 1024;

    const bf16x8* L8 = (const bf16x8*)ldsmem;
    char*         Lb = (char*)ldsmem;

    f32x4  acc[8][4] = {};
    bf16x8 af[4][2];
    bf16x8 bfr[2][2][2];

    auto stA = [&](int bufc, int tile, int half) {
        const bf16_t* g = Abase + (size_t)half * (128 * 1024) + tile * 64;
        char* l = Lb + (size_t)(bufc * 2 + 0) * 32768 + half * 16384 + woff;
        gld_lds16(g, l);
        gld_lds16(g + 64 * 1024, l + 8192);
    };
    auto stB = [&](int bufc, int tile, int half) {
        const bf16_t* g = Wbase + (size_t)half * (128 * 1024) + tile * 64;
        char* l = Lb + (size_t)(bufc * 2 + 1) * 32768 + half * 16384 + woff;
        gld_lds16(g, l);
        gld_lds16(g + 64 * 1024, l + 8192);
    };
    auto rdA = [&](int bufc, int mh) {
#pragma unroll
        for (int mf = 0; mf < 4; ++mf) {
            int rb = (bufc * 2 + 0) * 2048 + (wm * 128 + mh * 64 + mf * 16 + r16) * 8;
            af[mf][0] = L8[rb + x0];
            af[mf][1] = L8[rb + x1];
        }
    };
    auto rdB = [&](int bufc, int nh) {
#pragma unroll
        for (int nf = 0; nf < 2; ++nf) {
            int rb = (bufc * 2 + 1) * 2048 + (wn * 64 + nh * 32 + nf * 16 + r16) * 8;
            bfr[nh][nf][0] = L8[rb + x0];
            bfr[nh][nf][1] = L8[rb + x1];
        }
    };
    auto mmQ = [&](int mh, int nh) {
#pragma unroll
        for (int mf = 0; mf < 4; ++mf)
#pragma unroll
            for (int nf = 0; nf < 2; ++nf) {
                acc[mh*4+mf][nh*2+nf] = __builtin_amdgcn_mfma_f32_16x16x32_bf16(
                    af[mf][0], bfr[nh][nf][0], acc[mh*4+mf][nh*2+nf], 0, 0, 0);
                acc[mh*4+mf][nh*2+nf] = __builtin_amdgcn_mfma_f32_16x16x32_bf16(
                    af[mf][1], bfr[nh][nf][1], acc[mh*4+mf][nh*2+nf], 0, 0, 0);
            }
    };

#define G8_PH(mh, nh) do { G8_BAR; G8_LGKM;                      \
        __builtin_amdgcn_s_setprio(1); mmQ(mh, nh);              \
        __builtin_amdgcn_s_setprio(0); G8_SB; G8_BAR; G8_SB; } while (0)

    stA(0, 0, 0); stA(0, 0, 1);
    stB(0, 0, 0); stB(0, 0, 1);
    stB(1, 1, 0); stB(1, 1, 1);
    G8_VM4;
    G8_BAR; G8_SB;

    for (int i = 0; i < G8_NK / 2 - 1; ++i) {
        const int v1 = 2 * i + 1, u2 = 2 * i + 2, v2 = 2 * i + 3;
        rdA(0,0); rdB(0,0); stA(1, v1, 0);         G8_PH(0,0);
        rdB(0,1);           stA(1, v1, 1);         G8_PH(0,1);
        rdA(0,1);           stB(0, u2, 0);         G8_PH(1,0);
                            stB(0, u2, 1); G8_VM4; G8_PH(1,1);
        rdA(1,0); rdB(1,0); stA(0, u2, 0);         G8_PH(0,0);
        rdB(1,1);           stA(0, u2, 1);         G8_PH(0,1);
        rdA(1,1);           stB(1, v2, 0);         G8_PH(1,0);
                            stB(1, v2, 1); G8_VM4; G8_PH(1,1);
    }
    rdA(0,0); rdB(0,0); stA(1, G8_NK - 1, 0); G8_PH(0,0);
    rdB(0,1);           stA(1, G8_NK - 1, 1); G8_PH(0,1);
    rdA(0,1);                                 G8_PH(1,0);
                        G8_VM0;               G8_PH(1,1);
    rdA(1,0); rdB(1,0);                       G8_PH(0,0);
    rdB(1,1);                                 G8_PH(0,1);
    rdA(1,1);                                 G8_PH(1,0);
                                              G8_PH(1,1);

    bf16_t* Cb = C;
    int csub = 0;
    if (SPLIT && n0 >= 2048) { Cb = C2; csub = 2048; }

    float bv[4] = {0.f, 0.f, 0.f, 0.f};
    if (EPI >= 1) {
#pragma unroll
        for (int b = 0; b < 4; ++b) {
            int colg = n0 + wn * 64 + (b >> 1) * 32 + (b & 1) * 16 + r16;
            bv[b] = __bfloat162float(bias[colg]);
        }
    }
#pragma unroll
    for (int a = 0; a < 8; ++a) {
#pragma unroll
        for (int r = 0; r < 4; ++r) {
            int rowg = m0 + wm * 128 + (a >> 2) * 64 + (a & 3) * 16 + q * 4 + r;
#pragma unroll
            for (int b = 0; b < 4; ++b) {
                int colg = n0 + wn * 64 + (b >> 1) * 32 + (b & 1) * 16 + r16;
                float v = acc[a][b][r];
                if (EPI >= 1) v += bv[b];
                if (EPI == 2) v = v > 0.f ? v : 0.f;
                Cb[(size_t)rowg * ldc + (colg - csub)] = __float2bfloat16(v);
            }
        }
    }
#undef G8_PH
}

// ================== 8-phase 256x128 GEMM (narrow-N variant) ==================
template <int LDK, int NKT, int EPI, bool DYN>   // EPI: 0 none, 1 +bias
__global__ __launch_bounds__(512, 2)
void gemm8n(const bf16_t* __restrict__ A, const bf16_t* __restrict__ W,
            bf16_t* __restrict__ C, const bf16_t* __restrict__ bias, int ldc,
            const int* oflag, int c_row_off)
{
    __shared__ __align__(16) bf16_t ldsmem[2][24576];   // 49152 B per buf: A 32K | B 16K

    const int tid  = threadIdx.x;
    const int lane = tid & 63;
    const int wv   = tid >> 6;      // 0..7
    const int wm   = wv >> 2;       // 0..1 (128 rows)
    const int wn   = wv & 3;        // 0..3 (32 cols)
    const int r16  = lane & 15;
    const int q    = lane >> 4;
    const int m0   = blockIdx.x * 256;
    const int n0   = blockIdx.y * 128;

    const int x0 = q ^ (r16 & 7);
    const int x1 = (4 + q) ^ (r16 & 7);

    const int srow = tid >> 3;                       // 0..63
    const int scol = (tid & 7) ^ (srow & 7);
    const bf16_t* Abase = A + (size_t)(m0 + srow) * LDK + scol * 8;
    const bf16_t* Wbase = W + (size_t)(n0 + srow) * LDK + scol * 8;
    const int woff = wv * 1024;

    const bf16x8* L8 = (const bf16x8*)ldsmem;        // 16B chunk units
    char*         Lb = (char*)ldsmem;

    f32x4  acc[8][2] = {};
    bf16x8 af[4][2];          // [mf][kk]
    bf16x8 bfr[2][2];         // [nf][kk]

    auto stA = [&](int bufc, int tile, int half) {
        const bf16_t* g = Abase + (size_t)half * (128 * LDK) + tile * 64;
        char* l = Lb + (size_t)bufc * 49152 + half * 16384 + woff;
        gld_lds16(g, l);
        gld_lds16(g + (size_t)64 * LDK, l + 8192);
    };
    auto stB = [&](int bufc, int tile) {
        const bf16_t* g = Wbase + tile * 64;
        char* l = Lb + (size_t)bufc * 49152 + 32768 + woff;
        gld_lds16(g, l);
        gld_lds16(g + (size_t)64 * LDK, l + 8192);
    };
    auto rdA = [&](int bufc, int mh) {
#pragma unroll
        for (int mf = 0; mf < 4; ++mf) {
            int rb = bufc * 3072 + (wm * 128 + mh * 64 + mf * 16 + r16) * 8;
            af[mf][0] = L8[rb + x0];
            af[mf][1] = L8[rb + x1];
        }
    };
    auto rdB = [&](int bufc) {
#pragma unroll
        for (int nf = 0; nf < 2; ++nf) {
            int rb = bufc * 3072 + 2048 + (wn * 32 + nf * 16 + r16) * 8;
            bfr[nf][0] = L8[rb + x0];
            bfr[nf][1] = L8[rb + x1];
        }
    };
    auto mmP = [&](int mh) {
#pragma unroll
        for (int mf = 0; mf < 4; ++mf)
#pragma unroll
            for (int nf = 0; nf < 2; ++nf) {
                acc[mh*4+mf][nf] = __builtin_amdgcn_mfma_f32_16x16x32_bf16(
                    af[mf][0], bfr[nf][0], acc[mh*4+mf][nf], 0, 0, 0);
                acc[mh*4+mf][nf] = __builtin_amdgcn_mfma_f32_16x16x32_bf16(
                    af[mf][1], bfr[nf][1], acc[mh*4+mf][nf], 0, 0, 0);
            }
    };

#define GN_PH(mh) do { G8_BAR; G8_LGKM;                          \
        __builtin_amdgcn_s_setprio(1); mmP(mh);                  \
        __builtin_amdgcn_s_setprio(0); G8_SB; G8_BAR; G8_SB; } while (0)

    stA(0, 0, 0); stA(0, 0, 1);
    stB(0, 0);
    stB(1, 1);
    G8_VM2;
    G8_BAR; G8_SB;

    for (int i = 0; i < NKT / 2 - 1; ++i) {
        const int v1 = 2 * i + 1, u2 = 2 * i + 2, v2 = 2 * i + 3;
        rdA(0,0); rdB(0); stA(1, v1, 0); stA(1, v1, 1); GN_PH(0);   // P1
        rdA(0,1);         stB(0, u2); G8_VM2;           GN_PH(1);   // P2
        rdA(1,0); rdB(1); stA(0, u2, 0); stA(0, u2, 1); GN_PH(0);   // P3
        rdA(1,1);         stB(1, v2); G8_VM2;           GN_PH(1);   // P4
    }
    rdA(0,0); rdB(0); stA(1, NKT - 1, 0); stA(1, NKT - 1, 1); GN_PH(0);
    rdA(0,1);         G8_VM0;                                 GN_PH(1);
    rdA(1,0); rdB(1);                                         GN_PH(0);
    rdA(1,1);                                                 GN_PH(1);

    int of = 1;
    if constexpr (DYN) of = *oflag;
    float bv[2] = {0.f, 0.f};
    if (EPI >= 1) {
#pragma unroll
        for (int nf = 0; nf < 2; ++nf)
            bv[nf] = __bfloat162float(bias[n0 + wn * 32 + nf * 16 + r16]);
    }
#pragma unroll
    for (int a = 0; a < 8; ++a) {
#pragma unroll
        for (int r = 0; r < 4; ++r) {
            int rowg = m0 + wm * 128 + a * 16 + q * 4 + r;
#pragma unroll
            for (int nf = 0; nf < 2; ++nf) {
                int colg = n0 + wn * 32 + nf * 16 + r16;
                float v = acc[a][nf][r];
                if (EPI >= 1) v += bv[nf];
                if constexpr (DYN) {
                    size_t idx = (size_t)(c_row_off + rowg) * ldc + colg;
                    if (of) ((bf16_t*)C)[idx] = __float2bfloat16(v);
                    else    ((float*)C)[idx]  = v;
                } else {
                    C[(size_t)rowg * ldc + colg] = __float2bfloat16(v);
                }
            }
        }
    }
#undef GN_PH
}

// ---------- GEMM: 2-phase fallback for small/odd shapes ----------
#define TM 128
#define TN 128
#define TK 64

template <typename OutT, int EPI, bool DYN, bool EDGE>
__global__ __launch_bounds__(256, 2)
void gemm_bt(const bf16_t* __restrict__ A, int lda,
             const bf16_t* __restrict__ W, int ldw,
             OutT* __restrict__ C, int ldc,
             OutT* __restrict__ C2, int nsplit,
             const bf16_t* __restrict__ bias,
             int M, int N, int K,
             const int* oflag, int c_row_off)
{
    __shared__ bf16_t sA[TM * TK];
    __shared__ bf16_t sB[TN * TK];

    const int tid  = threadIdx.x;
    const int lane = tid & 63;
    const int wv   = tid >> 6;
    const int m0   = blockIdx.x * TM;
    const int n0   = blockIdx.y * TN;
    const int wm   = (wv >> 1) * 64;
    const int wn   = (wv & 1) * 64;
    const int r16  = lane & 15;
    const int q    = lane >> 4;

    int of = 1;
    if constexpr (DYN) of = *oflag;

    f32x4 acc[4][4] = {};

    for (int k0 = 0; k0 < K; k0 += TK) {
#pragma unroll
        for (int i = 0; i < 4; ++i) {
            int c    = (i * 4 + wv) * 64 + lane;
            int row  = c >> 3;
            int col8 = c & 7;
            const bf16_t* ga = A + (size_t)(m0 + row) * lda + k0 + col8 * 8;
            gld_lds16(ga, (char*)sA + (size_t)(i * 4 + wv) * 1024);
            int nrow = n0 + row;
            if (EDGE && nrow > N - 1) nrow = N - 1;
            const bf16_t* gb = W + (size_t)nrow * ldw + k0 + col8 * 8;
            gld_lds16(gb, (char*)sB + (size_t)(i * 4 + wv) * 1024);
        }
        __syncthreads();

        const bf16x8* sA8 = (const bf16x8*)sA;
        const bf16x8* sB8 = (const bf16x8*)sB;
#pragma unroll
        for (int kk = 0; kk < 2; ++kk) {
            bf16x8 af[4], bfr[4];
#pragma unroll
            for (int i = 0; i < 4; ++i)
                af[i] = sA8[(wm + i * 16 + r16) * 8 + kk * 4 + q];
#pragma unroll
            for (int j = 0; j < 4; ++j)
                bfr[j] = sB8[(wn + j * 16 + r16) * 8 + kk * 4 + q];
#pragma unroll
            for (int i = 0; i < 4; ++i)
#pragma unroll
                for (int j = 0; j < 4; ++j)
                    acc[i][j] = __builtin_amdgcn_mfma_f32_16x16x32_bf16(
                        af[i], bfr[j], acc[i][j], 0, 0, 0);
        }
        __syncthreads();
    }

    OutT* Cb = C;
    int csub = 0;
    if (C2 != nullptr && n0 >= nsplit) { Cb = C2; csub = nsplit; }

#pragma unroll
    for (int j = 0; j < 4; ++j) {
        int colg = n0 + wn + j * 16 + r16;
        if (EDGE && colg >= N) continue;
        float bv = 0.f;
        if (EPI >= 1) bv = __bfloat162float(bias[colg]);
#pragma unroll
        for (int i = 0; i < 4; ++i) {
#pragma unroll
            for (int r = 0; r < 4; ++r) {
                int rowg = m0 + wm + i * 16 + q * 4 + r;
                if (EDGE && rowg >= M) continue;
                float v = acc[i][j][r];
                if (EPI >= 1) v += bv;
                if (EPI == 2) v = v > 0.f ? v : 0.f;
                if (EPI == 3) v = softplus_fast(v);
                if constexpr (DYN) {
                    size_t idx = (size_t)(c_row_off + rowg) * ldc + colg;
                    if (of) ((bf16_t*)Cb)[idx] = __float2bfloat16(v);
                    else    ((float*)Cb)[idx]  = v;
                } else if constexpr (std::is_same<OutT, float>::value) {
                    Cb[(size_t)rowg * ldc + (colg - csub)] = v;
                } else {
                    Cb[(size_t)rowg * ldc + (colg - csub)] = __float2bfloat16(v);
                }
            }
        }
    }
}

// ---------- x_proj split-K GEMM ----------
__global__ __launch_bounds__(256, 2)
void gemm_xproj_splitk(const bf16_t* __restrict__ A,
                       const bf16_t* __restrict__ W,
                       float* __restrict__ part, int M)
{
    __shared__ bf16_t sA[TM * TK];
    __shared__ bf16_t sB[TN * TK];

    const int tid  = threadIdx.x;
    const int lane = tid & 63;
    const int wv   = tid >> 6;
    const int m0   = blockIdx.x * TM;
    const int kz   = blockIdx.z;
    const int wm   = (wv >> 1) * 64;
    const int wn   = (wv & 1) * 64;
    const int r16  = lane & 15;
    const int q    = lane >> 4;

    f32x4 acc[4][4] = {};

    const int kbeg = kz * (2048 / KS);
    for (int k0 = kbeg; k0 < kbeg + 2048 / KS; k0 += TK) {
#pragma unroll
        for (int i = 0; i < 4; ++i) {
            int c    = (i * 4 + wv) * 64 + lane;
            int row  = c >> 3;
            int col8 = c & 7;
            const bf16_t* ga = A + (size_t)(m0 + row) * DI + k0 + col8 * 8;
            gld_lds16(ga, (char*)sA + (size_t)(i * 4 + wv) * 1024);
            int nrow = row; if (nrow > 95) nrow = 95;
            const bf16_t* gb = W + (size_t)nrow * DI + k0 + col8 * 8;
            gld_lds16(gb, (char*)sB + (size_t)(i * 4 + wv) * 1024);
        }
        __syncthreads();

        const bf16x8* sA8 = (const bf16x8*)sA;
        const bf16x8* sB8 = (const bf16x8*)sB;
#pragma unroll
        for (int kk = 0; kk < 2; ++kk) {
            bf16x8 af[4], bfr[4];
#pragma unroll
            for (int i = 0; i < 4; ++i)
                af[i] = sA8[(wm + i * 16 + r16) * 8 + kk * 4 + q];
#pragma unroll
            for (int j = 0; j < 4; ++j)
                bfr[j] = sB8[(wn + j * 16 + r16) * 8 + kk * 4 + q];
#pragma unroll
            for (int i = 0; i < 4; ++i)
#pragma unroll
                for (int j = 0; j < 4; ++j)
                    acc[i][j] = __builtin_amdgcn_mfma_f32_16x16x32_bf16(
                        af[i], bfr[j], acc[i][j], 0, 0, 0);
        }
        __syncthreads();
    }

#pragma unroll
    for (int j = 0; j < 4; ++j) {
        int colg = wn + j * 16 + r16;
        if (colg >= 96) continue;
#pragma unroll
        for (int i = 0; i < 4; ++i) {
#pragma unroll
            for (int r = 0; r < 4; ++r) {
                int rowg = m0 + wm + i * 16 + q * 4 + r;
                part[((size_t)kz * M + rowg) * 96 + colg] = acc[i][j][r];
            }
        }
    }
}

__global__ __launch_bounds__(256)
void xproj_reduce(const float* __restrict__ part, bf16_t* __restrict__ xdbl,
                  float* __restrict__ x32, int M)
{
    int i = blockIdx.x * 256 + threadIdx.x;
    int n = M * 96;
    if (i >= n) return;
    float s = part[i] + part[(size_t)n + i] + part[2 * (size_t)n + i] + part[3 * (size_t)n + i];
    xdbl[i] = __float2bfloat16(s);
    if (x32) x32[i] = s;
}

// ---------- depthwise causal conv (k=4) + bias + SiLU ----------
__global__ __launch_bounds__(256)
void conv_silu_kernel(const bf16_t* __restrict__ u,
                      const bf16_t* __restrict__ cw,
                      const bf16_t* __restrict__ cb,
                      bf16_t* __restrict__ uc,
                      int Mrows)
{
    int idx = blockIdx.x * 256 + threadIdx.x;
    int eg  = idx & 255;
    int row = idx >> 8;
    if (row >= Mrows) return;
    int t = row & (LL - 1);
    int b = row >> 11;
    int e0 = eg * 8;

    float wf[32];
    {
        const uint4* wp = (const uint4*)(cw + (size_t)e0 * 4);
        uint4 w0 = wp[0], w1 = wp[1], w2 = wp[2], w3 = wp[3];
        unpack8(w0, wf); unpack8(w1, wf + 8); unpack8(w2, wf + 16); unpack8(w3, wf + 24);
    }
    float bias[8];
    unpack8(*(const uint4*)(cb + e0), bias);

    float uk[4][8];
#pragma unroll
    for (int k = 0; k < 4; ++k) {
        int tt = t - 3 + k;
        if (tt >= 0) {
            uint4 uv = *(const uint4*)(u + (size_t)(b * LL + tt) * DI + e0);
            unpack8(uv, uk[k]);
        } else {
#pragma unroll
            for (int j = 0; j < 8; ++j) uk[k][j] = 0.f;
        }
    }
    bf16_t out8[8];
#pragma unroll
    for (int j = 0; j < 8; ++j) {
        float a = bias[j];
#pragma unroll
        for (int k = 0; k < 4; ++k) a += wf[j * 4 + k] * uk[k][j];
        a = a / (1.f + __expf(-a));
        out8[j] = __float2bfloat16(a);
    }
    *(uint4*)(uc + (size_t)row * DI + e0) = *(uint4*)out8;
}

// ---------- chunked parallel scan: LDS-staged tiles, counted-vmcnt pipeline ---
__global__ __launch_bounds__(256, 4)
void scan_pass1(const bf16_t* __restrict__ uc, const bf16_t* __restrict__ dtb,
                const float* __restrict__ x32, const bf16_t* __restrict__ A_log,
                float* __restrict__ hfin, float* __restrict__ Ssum, int lgG)
{
    __shared__ __align__(16) char sm1[36864];   // U[2] 0/8K, D[2] 16/24K, B 32K..36K
    const int tid  = threadIdx.x;
    const int lane = tid & 63;
    const int wv   = tid >> 6;
    const int bid  = blockIdx.x;
    const int eb   = bid & 7;
    const int rem  = bid >> 3;
    const int b    = rem & ((1 << lgG) - 1);
    const int chunk = rem >> lgG;
    const int e0   = eb * 256;
    const int e    = e0 + tid;
    const int t0   = chunk * CL;

    const bf16_t* ub = uc  + (size_t)(b * LL + t0) * DI;
    const bf16_t* db = dtb + (size_t)(b * LL + t0) * DI;
    const float*  xr = x32 + (size_t)(b * LL + t0) * 96 + 64;

    char* const U[2] = { sm1, sm1 + 8192 };
    char* const D[2] = { sm1 + 16384, sm1 + 24576 };
    char* const Bl   = sm1 + 32768;

    auto stage2 = [&](const bf16_t* src, char* dst, int trow0) {
        const int c8 = (lane & 31) * 8;
        const int r0 = 2 * wv + (lane >> 5);
        gld_lds16(src + (size_t)(trow0 + r0) * DI + e0 + c8, dst + wv * 1024 + lane * 16);
        gld_lds16(src + (size_t)(trow0 + r0 + 8) * DI + e0 + c8, dst + (wv + 4) * 1024 + lane * 16);
    };
    // stage whole chunk's B panel (64 steps x 64B): 256 chunks of 16B, 1/thread
    {
        int s = tid >> 2, p = tid & 3;
        gld_lds16(xr + (size_t)s * 96 + p * 4, Bl + tid * 16);      // 1 op
    }
    stage2(ub, U[0], 0);  stage2(db, D[0], 0);                      // 4 ops
    stage2(ub, U[1], TT); stage2(db, D[1], TT);                     // 4 ops

    // prologue (covers staging latency): 16 exps
    float alf[16];
    {
        uint4 v0 = *(const uint4*)(A_log + (size_t)e * NS);
        uint4 v1 = *(const uint4*)(A_log + (size_t)e * NS + 8);
        unpack8(v0, alf); unpack8(v1, alf + 8);
    }
    float a0 = -__expf(alf[0]) * LOG2E;
    float Aa2[16];
    int fast = 1;
#pragma unroll
    for (int n = 0; n < 16; ++n) {
        Aa2[n] = -__expf(alf[n]) * LOG2E;
        float ideal = (float)(n + 1) * a0;
        fast = fast && (fabsf(Aa2[n] - ideal) <= 0.02f * fabsf(ideal));
    }
    int allfast = __syncthreads_and(fast);

    float h[16];
#pragma unroll
    for (int j = 0; j < 16; ++j) h[j] = 0.f;
    float Ss = 0.f;

#define P1_CMP(K, FAST) do {                                                  \
        const char* Ut = U[(K) & 1]; const char* Dt = D[(K) & 1];             \
        _Pragma("unroll")                                                     \
        for (int t = 0; t < TT; ++t) {                                        \
            float cu  = __bfloat162float(*(const bf16_t*)(Ut + t * 512 + tid * 2)); \
            float cdt = __bfloat162float(*(const bf16_t*)(Dt + t * 512 + tid * 2)); \
            const float* bc = (const float*)(Bl + ((K) * TT + t) * 64);       \
            float du = cdt * cu; Ss += cdt;                                   \
            if (FAST) {                                                       \
                float r = EXP2F(cdt * a0);                                    \
                float r2 = r * r, r4 = r2 * r2, r8 = r4 * r4;                 \
                float dA = r, dB = r8 * r;                                    \
                _Pragma("unroll")                                             \
                for (int j = 0; j < 8; ++j) { h[j] = dA * h[j] + du * bc[j]; dA *= r; } \
                _Pragma("unroll")                                             \
                for (int j = 8; j < 16; ++j) { h[j] = dB * h[j] + du * bc[j]; dB *= r; } \
            } else {                                                          \
                _Pragma("unroll")                                             \
                for (int j = 0; j < 16; ++j) {                                \
                    float dA = EXP2F(cdt * Aa2[j]);                           \
                    h[j] = dA * h[j] + du * bc[j]; }                          \
            }                                                                 \
        } } while (0)

#define P1_SEQ(FAST) do {                                                     \
        G8_VM4; G8_BAR; G8_SB;                                                \
        P1_CMP(0, FAST); G8_LGKM; G8_BAR; G8_SB;                              \
        stage2(ub, U[0], 2 * TT); stage2(db, D[0], 2 * TT);                   \
        G8_VM4; G8_BAR; G8_SB;                                                \
        P1_CMP(1, FAST); G8_LGKM; G8_BAR; G8_SB;                              \
        stage2(ub, U[1], 3 * TT); stage2(db, D[1], 3 * TT);                   \
        G8_VM4; G8_BAR; G8_SB;                                                \
        P1_CMP(2, FAST); G8_LGKM; G8_BAR; G8_SB;                              \
        G8_VM0; G8_BAR; G8_SB;                                                \
        P1_CMP(3, FAST);                                                      \
    } while (0)

    if (allfast) P1_SEQ(true); else P1_SEQ(false);
#undef P1_SEQ
#undef P1_CMP

    size_t base = (size_t)(b * NC + chunk) * NS * DI + e;
#pragma unroll
    for (int j = 0; j < 16; ++j) hfin[base + (size_t)j * DI] = h[j];
    Ssum[(size_t)(b * NC + chunk) * DI + e] = Ss;
}

__global__ __launch_bounds__(256)
void scan_pass2(const float* __restrict__ Ssum, const bf16_t* __restrict__ A_log,
                float* __restrict__ hfin)
{
    int idx = blockIdx.x * 256 + threadIdx.x;
    int e = idx & (DI - 1);
    int rem = idx >> 11;
    int n = rem & (NS - 1);
    int b = rem >> 4;
    float Aa2 = -__expf(__bfloat162float(A_log[(size_t)e * NS + n])) * LOG2E;
    float h = 0.f;
    for (int c = 0; c < NC; ++c) {
        size_t a = ((size_t)(b * NC + c) * NS + n) * DI + e;
        float S  = Ssum[(size_t)(b * NC + c) * DI + e];
        float hf = hfin[a];
        hfin[a] = h;
        h = EXP2F(Aa2 * S) * h + hf;
    }
}

__global__ __launch_bounds__(256, 2)
void scan_pass3(const bf16_t* __restrict__ uc, const bf16_t* __restrict__ dtb,
                const float* __restrict__ x32, bf16_t* __restrict__ zy,
                const bf16_t* __restrict__ A_log, const bf16_t* __restrict__ Dp,
                const float* __restrict__ hin, int lgG)
{
    __shared__ __align__(16) char sm3[65536];  // U 0/8K, D 16/24K, Z 32/40K, Y 48K, BC 56K
    const int tid  = threadIdx.x;
    const int lane = tid & 63;
    const int wv   = tid >> 6;
    const int bid  = blockIdx.x;
    const int eb   = bid & 7;
    const int rem  = bid >> 3;
    const int b    = rem & ((1 << lgG) - 1);
    const int chunk = rem >> lgG;
    const int e0   = eb * 256;
    const int e    = e0 + tid;
    const int t0   = chunk * CL;

    const bf16_t* ub = uc  + (size_t)(b * LL + t0) * DI;
    const bf16_t* db = dtb + (size_t)(b * LL + t0) * DI;
    bf16_t*       zb = zy  + (size_t)(b * LL + t0) * DI;   // z in, y out
    const float*  xr = x32 + (size_t)(b * LL + t0) * 96 + 64;

    char* const U[2] = { sm3, sm3 + 8192 };
    char* const D[2] = { sm3 + 16384, sm3 + 24576 };
    char* const Z[2] = { sm3 + 32768, sm3 + 40960 };
    char* const Y    = sm3 + 49152;
    char* const BC   = sm3 + 57344;

    auto stage2 = [&](const bf16_t* src, char* dst, int trow0) {
        const int c8 = (lane & 31) * 8;
        const int r0 = 2 * wv + (lane >> 5);
        gld_lds16(src + (size_t)(trow0 + r0) * DI + e0 + c8, dst + wv * 1024 + lane * 16);
        gld_lds16(src + (size_t)(trow0 + r0 + 8) * DI + e0 + c8, dst + (wv + 4) * 1024 + lane * 16);
    };
    // stage whole chunk's B+C panel (64 steps x 128B = 8KB): 512 chunks, 2/thread
    {
        int s1 = tid >> 3, p1 = tid & 7;
        gld_lds16(xr + (size_t)s1 * 96 + p1 * 4, BC + tid * 16);
        gld_lds16(xr + (size_t)(s1 + 32) * 96 + p1 * 4, BC + 4096 + tid * 16);
    }                                                                // 2 ops
    stage2(ub, U[0], 0);  stage2(db, D[0], 0);  stage2(zb, Z[0], 0);   // 6
    stage2(ub, U[1], TT); stage2(db, D[1], TT); stage2(zb, Z[1], TT);  // 6

    // prologue (covers staging latency)
    float alf[16];
    {
        uint4 v0 = *(const uint4*)(A_log + (size_t)e * NS);
        uint4 v1 = *(const uint4*)(A_log + (size_t)e * NS + 8);
        unpack8(v0, alf); unpack8(v1, alf + 8);
    }
    float a0 = -__expf(alf[0]) * LOG2E;
    float Aa2[16];
    int fast = 1;
#pragma unroll
    for (int n = 0; n < 16; ++n) {
        Aa2[n] = -__expf(alf[n]) * LOG2E;
        float ideal = (float)(n + 1) * a0;
        fast = fast && (fabsf(Aa2[n] - ideal) <= 0.02f * fabsf(ideal));
    }
    int allfast = __syncthreads_and(fast);

    float Dv = __bfloat162float(Dp[e]);
    size_t hbase = (size_t)(b * NC + chunk) * NS * DI + e;
    float h[16];
#pragma unroll
    for (int j = 0; j < 16; ++j) h[j] = hin[hbase + (size_t)j * DI];

    auto yflush = [&](int K) {
        const int r0 = tid >> 5;
        const int c  = (tid & 31) * 16;
        uint4 v0 = *(const uint4*)(Y + r0 * 512 + c);
        uint4 v1 = *(const uint4*)(Y + (r0 + 8) * 512 + c);
        *(uint4*)(zb + (size_t)(K * TT + r0) * DI + e0 + (tid & 31) * 8)     = v0;
        *(uint4*)(zb + (size_t)(K * TT + r0 + 8) * DI + e0 + (tid & 31) * 8) = v1;
    };

#define P3_CMP(K, FAST) do {                                                  \
        const char* Ut = U[(K) & 1]; const char* Dt = D[(K) & 1];             \
        const char* Zt = Z[(K) & 1];                                          \
        _Pragma("unroll")                                                     \
        for (int t = 0; t < TT; ++t) {                                        \
            float cu  = __bfloat162float(*(const bf16_t*)(Ut + t * 512 + tid * 2)); \
            float cdt = __bfloat162float(*(const bf16_t*)(Dt + t * 512 + tid * 2)); \
            float cz  = __bfloat162float(*(const bf16_t*)(Zt + t * 512 + tid * 2)); \
            const float* bc = (const float*)(BC + ((K) * TT + t) * 128);      \
            float du = cdt * cu;                                              \
            if (FAST) {                                                       \
                float r = EXP2F(cdt * a0);                                    \
                float r2 = r * r, r4 = r2 * r2, r8 = r4 * r4;                 \
                float dA = r, dB = r8 * r;                                    \
                _Pragma("unroll")                                             \
                for (int j = 0; j < 8; ++j) { h[j] = dA * h[j] + du * bc[j]; dA *= r; } \
                _Pragma("unroll")                                             \
                for (int j = 8; j < 16; ++j) { h[j] = dB * h[j] + du * bc[j]; dB *= r; } \
            } else {                                                          \
                _Pragma("unroll")                                             \
                for (int j = 0; j < 16; ++j) {                                \
                    float dA = EXP2F(cdt * Aa2[j]);                           \
                    h[j] = dA * h[j] + du * bc[j]; }                          \
            }                                                                 \
            float y1 = 0.f, y2 = 0.f;                                         \
            _Pragma("unroll")                                                 \
            for (int j = 0; j < 8; ++j)  y1 += h[j] * bc[16 + j];             \
            _Pragma("unroll")                                                 \
            for (int j = 8; j < 16; ++j) y2 += h[j] * bc[16 + j];             \
            float yv  = y1 + y2;                                              \
            float sil = cz / (1.f + __expf(-cz));                             \
            *(bf16_t*)(Y + t * 512 + tid * 2) =                               \
                __float2bfloat16((yv + cu * Dv) * sil);                       \
        } } while (0)

#define P3_SEQ(FAST) do {                                                     \
        G8_VM6; G8_BAR; G8_SB;                                                \
        P3_CMP(0, FAST); G8_LGKM; G8_BAR; G8_SB;                              \
        yflush(0);                                                            \
        stage2(ub, U[0], 2*TT); stage2(db, D[0], 2*TT); stage2(zb, Z[0], 2*TT); \
        G8_VM8; G8_BAR; G8_SB;                                                \
        P3_CMP(1, FAST); G8_LGKM; G8_BAR; G8_SB;                              \
        yflush(1);                                                            \
        stage2(ub, U[1], 3*TT); stage2(db, D[1], 3*TT); stage2(zb, Z[1], 3*TT); \
        G8_VM8; G8_BAR; G8_SB;                                                \
        P3_CMP(2, FAST); G8_LGKM; G8_BAR; G8_SB;                              \
        yflush(2);                                                            \
        G8_VM2; G8_BAR; G8_SB;                                                \
        P3_CMP(3, FAST); G8_LGKM; G8_BAR; G8_SB;                              \
        yflush(3);                                                            \
    } while (0)

    if (allfast) P3_SEQ(true); else P3_SEQ(false);
#undef P3_SEQ
#undef P3_CMP
}

// ---------- serial scan fallback (reads bf16 xdbl) ----------
__global__ __launch_bounds__(64)
void scan_kernel(const bf16_t* __restrict__ uc,
                 const bf16_t* __restrict__ dt,
                 const bf16_t* __restrict__ xdbl,
                 bf16_t* __restrict__ zy,
                 const bf16_t* __restrict__ A_log,
                 const bf16_t* __restrict__ Dp)
{
    int idx = blockIdx.x * 64 + threadIdx.x;
    int e = idx & (DI - 1);
    int b = idx >> 11;

    float Aa[NS];
#pragma unroll
    for (int n = 0; n < NS; ++n)
        Aa[n] = -__expf(__bfloat162float(A_log[e * NS + n]));
    float Dv = __bfloat162float(Dp[e]);
    float h[NS];
#pragma unroll
    for (int n = 0; n < NS; ++n) h[n] = 0.f;

    const bf16_t* up  = uc   + (size_t)b * LL * DI + e;
    const bf16_t* dp  = dt   + (size_t)b * LL * DI + e;
    const bf16_t* zp  = zy   + (size_t)b * LL * DI + e;
    const bf16_t* bcp = xdbl + (size_t)b * LL * 96 + 64;
    bf16_t*       yp  = zy   + (size_t)b * LL * DI + e;

    float nu  = __bfloat162float(*up);
    float ndt = __bfloat162float(*dp);
    float nz  = __bfloat162float(*zp);
    uint4 nb0 = *(const uint4*)(bcp);
    uint4 nb1 = *(const uint4*)(bcp + 8);
    uint4 nc0 = *(const uint4*)(bcp + 16);
    uint4 nc1 = *(const uint4*)(bcp + 24);

    for (int t = 0; t < LL; ++t) {
        float cu = nu, cdt = ndt, cz = nz;
        uint4 b0 = nb0, b1 = nb1, c0 = nc0, c1 = nc1;
        if (t + 1 < LL) {
            up += DI; dp += DI; zp += DI; bcp += 96;
            nu  = __bfloat162float(*up);
            ndt = __bfloat162float(*dp);
            nz  = __bfloat162float(*zp);
            nb0 = *(const uint4*)(bcp);
            nb1 = *(const uint4*)(bcp + 8);
            nc0 = *(const uint4*)(bcp + 16);
            nc1 = *(const uint4*)(bcp + 24);
        }
        float Bv[NS], Cv[NS];
        unpack8(b0, Bv); unpack8(b1, Bv + 8);
        unpack8(c0, Cv); unpack8(c1, Cv + 8);

        float du = cdt * cu;
        float yv = 0.f;
#pragma unroll
        for (int n = 0; n < NS; ++n) {
            float dA = __expf(cdt * Aa[n]);
            h[n] = dA * h[n] + du * Bv[n];
            yv += h[n] * Cv[n];
        }
        float sil  = cz / (1.f + __expf(-cz));
        float outv = (yv + cu * Dv) * sil;
        *yp = __float2bfloat16(outv);
        yp += DI;
    }
}

// ---------- launcher ----------
extern "C" void kernel_launch(void* const* d_in, const int* in_sizes, int n_in,
                              void* d_out, int out_size, void* d_ws, size_t ws_size,
                              hipStream_t stream)
{
    char* ws = (char*)d_ws;
    int* flag = (int*)ws;
    size_t cur = 256;
    auto alloc = [&](size_t bytes) { bf16_t* p = (bf16_t*)(ws + cur); cur += bytes; return p; };

    const size_t o_xb = cur;
    bf16_t* xb   = alloc((size_t)MTOK * DM * 2);      // 16 MiB
    bf16_t* w_in = alloc((size_t)2 * DI * DM * 2);    //  8 MiB
    bf16_t* w_o  = alloc((size_t)DM * DI * 2);
    bf16_t* w_l1 = alloc((size_t)DFF * DM * 2);
    bf16_t* w_l2 = alloc((size_t)DM * DFF * 2);
    bf16_t* w_xp = alloc((size_t)96 * DI * 2);
    bf16_t* w_dt = alloc((size_t)DI * DTR * 2);
    bf16_t* cw   = alloc((size_t)DI * 4 * 2);
    bf16_t* cb   = alloc((size_t)DI * 2);
    bf16_t* dpb  = alloc((size_t)DI * 2);
    bf16_t* alog = alloc((size_t)DI * NS * 2);
    bf16_t* dd   = alloc((size_t)DI * 2);
    bf16_t* l1b  = alloc((size_t)DFF * 2);
    bf16_t* l2b  = alloc((size_t)DM * 2 + 2048);
    cur = (cur + 255) & ~(size_t)255;
    const size_t o_pipe = cur;

    detect_dtype_kernel<<<1, 256, 0, stream>>>((const unsigned*)d_in[0], flag);

    {
        CvtDesc d;
        const void* ss[14] = { d_in[0], d_in[1], d_in[9], d_in[10], d_in[12], d_in[4],
                               d_in[5], d_in[2], d_in[3], d_in[6], d_in[7], d_in[8],
                               d_in[11], d_in[13] };
        bf16_t* dd_[14]    = { xb, w_in, w_o, w_l1, w_l2, w_xp,
                               w_dt, cw, cb, dpb, alog, dd, l1b, l2b };
        size_t  nn[14]     = { (size_t)MTOK*DM, (size_t)2*DI*DM, (size_t)DM*DI,
                               (size_t)DFF*DM, (size_t)DM*DFF, (size_t)96*DI,
                               (size_t)DI*DTR, (size_t)DI*4, (size_t)DI, (size_t)DI,
                               (size_t)DI*NS, (size_t)DI, (size_t)DFF, (size_t)DM };
        int c = 0; d.cum[0] = 0;
        for (int i = 0; i < 14; ++i) {
            d.src[i] = ss[i]; d.dst[i] = dd_[i];
            c += (int)(nn[i] / 8); d.cum[i + 1] = c;
        }
        convert_all<<<(c + 255) / 256, 256, 0, stream>>>(d, flag, c);
    }

    auto pipe = [&](int Gq) { return (size_t)Gq * LL * 96 * 2 + 3ull * Gq * LL * DI * 2; };
    auto scr  = [&](int Gq) {
        return (size_t)Gq * NC * NS * DI * 4 + (size_t)Gq * NC * DI * 4 + (size_t)Gq * LL * 96 * 4;
    };

    int G; bool chunked; size_t scr_off;
    if      (ws_size >= o_pipe + pipe(4))            { G = 4; chunked = true;  scr_off = o_xb; }
    else if (ws_size >= o_pipe + pipe(2) + scr(2))   { G = 2; chunked = true;  scr_off = o_pipe + pipe(2); }
    else if (ws_size >= o_pipe + pipe(1) + scr(1))   { G = 1; chunked = true;  scr_off = o_pipe + pipe(1); }
    else                                             { G = 1; chunked = false; scr_off = o_pipe + pipe(1); }
    const int lgG = (G == 4) ? 2 : (G == 2 ? 1 : 0);

    const size_t hfin_sz = (size_t)G * NC * NS * DI * 4;
    const size_t ssum_sz = (size_t)G * NC * DI * 4;

    for (int g0 = 0; g0 < BB; g0 += G) {
        const int    Mg      = G * LL;
        const size_t xdbl_sz = (size_t)Mg * 96 * 2;
        const size_t big     = (size_t)Mg * DI * 2;

        bf16_t* xdbl = (bf16_t*)(ws + o_pipe);
        bf16_t* ubuf = (bf16_t*)(ws + o_pipe + xdbl_sz);
        bf16_t* dtb  = ubuf;
        bf16_t* zbuf = (bf16_t*)(ws + o_pipe + xdbl_sz + big);
        bf16_t* uc   = (bf16_t*)(ws + o_pipe + xdbl_sz + 2 * big);
        bf16_t* my   = uc;
        bf16_t* hh   = (bf16_t*)(ws + o_pipe);
        float*  xpp  = (float*)(ws + scr_off);
        float*  x32  = chunked ? (float*)(ws + scr_off + hfin_sz + ssum_sz) : nullptr;

        const bf16_t* x_g = xb + (size_t)g0 * LL * DM;

        dim3 blk(256);
        const int gx = Mg / TM;

        // 1. in_proj merged (N=4096, K=1024): 8-phase 256^2; cols<2048 -> ubuf, else zbuf
        gemm8<0, true><<<dim3(Mg / 256, 16), 512, 0, stream>>>(
            x_g, w_in, ubuf, zbuf, nullptr, DI);
        // 2. depthwise conv + SiLU -> uc
        conv_silu_kernel<<<Mg, 256, 0, stream>>>(ubuf, cw, cb, uc, Mg);
        // 3. x_proj split-K -> partials -> xdbl (bf16) + x32 (fp32)
        gemm_xproj_splitk<<<dim3(gx, 1, KS), blk, 0, stream>>>(uc, w_xp, xpp, Mg);
        xproj_reduce<<<(Mg * 96 + 255) / 256, 256, 0, stream>>>(xpp, xdbl, x32, Mg);
        // 4. dt_proj + fast softplus -> dtb
        gemm_bt<bf16_t, 3, false, false><<<dim3(gx, DI / TN), blk, 0, stream>>>(
            xdbl, 96, w_dt, DTR, dtb, DI, nullptr, 0, dpb, Mg, DI, DTR, nullptr, 0);
        // 5. selective scan + gating; y overwrites zbuf (LDS-staged tiles)
        if (chunked) {
            float* hfin = (float*)(ws + scr_off);
            float* Ssum = (float*)(ws + scr_off + hfin_sz);
            scan_pass1<<<G * NC * (DI / 256), 256, 0, stream>>>(uc, dtb, x32, alog, hfin, Ssum, lgG);
            scan_pass2<<<G * (NS * DI / 256), 256, 0, stream>>>(Ssum, alog, hfin);
            scan_pass3<<<G * NC * (DI / 256), 256, 0, stream>>>(uc, dtb, x32, zbuf, alog, dd, hfin, lgG);
        } else {
            scan_kernel<<<(G * DI) / 64, 64, 0, stream>>>(uc, dtb, xdbl, zbuf, alog, dd);
        }
        // 6. out_proj -> my (8-phase 256x128, K=2048)
        gemm8n<2048, 32, 0, false><<<dim3(Mg / 256, DM / 128), 512, 0, stream>>>(
            zbuf, w_o, my, nullptr, DM, nullptr, 0);
        // 7. lin1 + bias + relu -> hh (8-phase 256^2)
        gemm8<2, false><<<dim3(Mg / 256, 16), 512, 0, stream>>>(
            my, w_l1, hh, nullptr, l1b, DFF);
        // 8. lin2 + bias -> d_out (8-phase 256x128, K=4096, dtype per flag)
        gemm8n<4096, 64, 1, true><<<dim3(Mg / 256, DM / 128), 512, 0, stream>>>(
            hh, w_l2, (bf16_t*)d_out, l2b, DM, (const int*)ws, g0 * LL);
    }
}